// Round 17
// baseline (3059.864 us; speedup 1.0000x reference)
//
#include <hip/hip_runtime.h>
#include <hip/hip_bf16.h>
#include <math.h>

#define BB 64
#define IMG 224
#define PP 16
#define CIN 3
#define DM 192
#define DEPTH 24
#define DSTATE 16
#define DINNER 384
#define DTR 12
#define DCONV 4
#define NP 196              // (224/16)^2
#define RTOT (BB * NP)      // 12544 rows
#define CHUNKS 14
#define LC 14               // NP / CHUNKS
#define NCMB (2 * DSTATE + DINNER)   // 416 = B,C (32) + dt (384)

typedef short bf16x8 __attribute__((ext_vector_type(8)));
typedef float f32x4 __attribute__((ext_vector_type(4)));

__device__ inline unsigned short f2bf_rne(float f) {
    unsigned u = __float_as_uint(f);
    unsigned r = u + 0x7fffu + ((u >> 16) & 1u);
    return (unsigned short)(r >> 16);
}
__device__ inline float bf2f(unsigned short s) {
    return __uint_as_float(((unsigned)s) << 16);
}

// ---------------- im2col for patch embed, emitting bf16 ----------------
__global__ __launch_bounds__(256) void im2col_pack_kernel(const float* __restrict__ img,
                                                          short* __restrict__ colH) {
    size_t idx = (size_t)blockIdx.x * 256 + threadIdx.x;
    if (idx >= (size_t)RTOT * 768) return;
    int t = (int)(idx % 768);
    size_t r = idx / 768;
    int l = (int)(r % NP);
    int b = (int)(r / NP);
    int ph = l / 14, pw = l % 14;
    int ci = t / 256, rem = t % 256;
    int i = rem / 16, j = rem % 16;
    float v = img[(((size_t)b * CIN + ci) * IMG + ph * 16 + i) * IMG + pw * 16 + j];
    colH[idx] = (short)f2bf_rne(v);
}

// ---------------- weight pack: fp32[NE] -> bf16 ----------------
__global__ __launch_bounds__(256) void pack_w_kernel(const float* __restrict__ W,
                                                     short* __restrict__ Wh, int NE) {
    int i = blockIdx.x * 256 + threadIdx.x;
    if (i * 4 >= NE) return;
    float4 v = *(const float4*)&W[i * 4];
    short4 h;
    h.x = (short)f2bf_rne(v.x);
    h.y = (short)f2bf_rne(v.y);
    h.z = (short)f2bf_rne(v.z);
    h.w = (short)f2bf_rne(v.w);
    *(short4*)&Wh[i * 4] = h;
}

// ---------------- combined xproj weight: [DEPTH][416][384] bf16 ----------------
__global__ __launch_bounds__(256) void wcmb_kernel(const float* __restrict__ xpw,
                                                   const float* __restrict__ dtw,
                                                   short* __restrict__ wCmb) {
    int idx = blockIdx.x * 256 + threadIdx.x;
    if (idx >= DEPTH * NCMB * DINNER) return;
    int layer = idx / (NCMB * DINNER);
    int rem = idx % (NCMB * DINNER);
    int n = rem / DINNER;
    int k = rem % DINNER;
    const float* xp = xpw + (size_t)layer * 44 * DINNER;
    float v;
    if (n < 32) {
        v = xp[(DTR + n) * DINNER + k];
    } else {
        int d = n - 32;
        const float* w = dtw + ((size_t)layer * DINNER + d) * DTR;
        v = 0.f;
#pragma unroll
        for (int j = 0; j < DTR; j++) v += w[j] * xp[j * DINNER + k];
    }
    wCmb[idx] = (short)f2bf_rne(v);
}

// ---------------- cross-layer fused weight: Wcross[l] = Win[l+1] @ Wout[l] ----------------
// [23][768][384] bf16: Wcross[n][k] = sum_m in_w[l+1][n][m] * outw[l][m][k].
// Thread computes 4 k-outputs (float4 B loads, broadcast A).
__global__ __launch_bounds__(256) void wcross_kernel(const float* __restrict__ in_w,
                                                     const float* __restrict__ outw,
                                                     short* __restrict__ wCross) {
    int idx = blockIdx.x * 256 + threadIdx.x;
    if (idx >= (DEPTH - 1) * 768 * (DINNER / 4)) return;
    int lid = idx / (768 * (DINNER / 4));        // 0..22 (target layer lid+1)
    int rem = idx % (768 * (DINNER / 4));
    int n = rem / (DINNER / 4);
    int k4 = (rem % (DINNER / 4)) * 4;
    const float* A = in_w + ((size_t)(lid + 1)) * 768 * DM + (size_t)n * DM;
    const float* Bp = outw + (size_t)lid * DM * DINNER + k4;
    float4 acc = make_float4(0.f, 0.f, 0.f, 0.f);
    for (int m = 0; m < DM; m++) {
        float w = A[m];
        float4 o = *(const float4*)&Bp[(size_t)m * DINNER];
        acc.x = fmaf(w, o.x, acc.x);
        acc.y = fmaf(w, o.y, acc.y);
        acc.z = fmaf(w, o.z, acc.z);
        acc.w = fmaf(w, o.w, acc.w);
    }
    short4 h;
    h.x = (short)f2bf_rne(acc.x);
    h.y = (short)f2bf_rne(acc.y);
    h.z = (short)f2bf_rne(acc.z);
    h.w = (short)f2bf_rne(acc.w);
    *(short4*)&wCross[(size_t)lid * 768 * DINNER + (size_t)n * DINNER + k4] = h;
}

// ---------------- bf16 MFMA GEMM, double-buffered LDS, 1 barrier/k-iter ----------------
template<int BM, int BN>
__global__ __launch_bounds__(256) void gemm_pk_kernel(const short* __restrict__ Ah,
                                                      const short* __restrict__ Bh,
                                                      float* __restrict__ C,
                                                      short* __restrict__ CBf,
                                                      const float* __restrict__ bias,
                                                      int M, int N, int K, int Kc) {
    constexpr int BK = 32;
    constexpr int LDSS = BK + 8;
    constexpr int WR = BM / 64;
    constexpr int WC = 4 / WR;
    constexpr int NJ = BN / WC / 16;
    constexpr int A8 = BM / 64;
    constexpr int B8 = BN / 64;
    __shared__ short As[2][BM * LDSS];
    __shared__ short Bs[2][BN * LDSS];

    const int tid = threadIdx.x;
    const int lane = tid & 63;
    const int wid = tid >> 6;
    const int wr = wid / WC, wc = wid % WC;
    const int row0 = blockIdx.y * BM, col0 = blockIdx.x * BN;
    const int kbase = blockIdx.z * Kc;
    const bf16x8 ZV = {0, 0, 0, 0, 0, 0, 0, 0};

    bf16x8 aPh[A8], bPh[B8];
    f32x4 acc[4][NJ] = {};

    auto loadG = [&](int k0) {
#pragma unroll
        for (int i = 0; i < A8; i++) {
            int lin = tid + i * 256;
            int r = lin >> 2, cg = (lin & 3) * 8;
            aPh[i] = *(const bf16x8*)&Ah[(size_t)(row0 + r) * K + k0 + cg];
        }
#pragma unroll
        for (int i = 0; i < B8; i++) {
            int lin = tid + i * 256;
            int r = lin >> 2, cg = (lin & 3) * 8;
            int n = col0 + r;
            bPh[i] = (n < N) ? *(const bf16x8*)&Bh[(size_t)n * K + k0 + cg] : ZV;
        }
    };
    auto storeLDS = [&](int p) {
#pragma unroll
        for (int i = 0; i < A8; i++) {
            int lin = tid + i * 256;
            int r = lin >> 2, cg = (lin & 3) * 8;
            *(bf16x8*)&As[p][r * LDSS + cg] = aPh[i];
        }
#pragma unroll
        for (int i = 0; i < B8; i++) {
            int lin = tid + i * 256;
            int r = lin >> 2, cg = (lin & 3) * 8;
            *(bf16x8*)&Bs[p][r * LDSS + cg] = bPh[i];
        }
    };
    auto compute = [&](int p) {
        const int fr = lane & 15;
        const int kg = (lane >> 4) * 8;
        bf16x8 aH[4], bH[NJ];
#pragma unroll
        for (int i = 0; i < 4; i++)
            aH[i] = *(const bf16x8*)&As[p][(wr * 64 + i * 16 + fr) * LDSS + kg];
#pragma unroll
        for (int j = 0; j < NJ; j++)
            bH[j] = *(const bf16x8*)&Bs[p][(wc * (BN / WC) + j * 16 + fr) * LDSS + kg];
#pragma unroll
        for (int i = 0; i < 4; i++)
#pragma unroll
            for (int j = 0; j < NJ; j++)
                acc[i][j] = __builtin_amdgcn_mfma_f32_16x16x32_bf16(aH[i], bH[j], acc[i][j], 0, 0, 0);
    };

    loadG(kbase);
    storeLDS(0);
    __syncthreads();
    int p = 0;
    for (int k0 = kbase + BK;; k0 += BK) {
        const bool has_next = (k0 < kbase + Kc);
        if (has_next) loadG(k0);
        compute(p);
        if (!has_next) break;
        storeLDS(p ^ 1);
        __syncthreads();
        p ^= 1;
    }

    const bool direct = (gridDim.z == 1);
    float* Cout = C + (size_t)blockIdx.z * M * N;
    const int crow = (lane >> 4) * 4;
    const int ccol = lane & 15;
#pragma unroll
    for (int i = 0; i < 4; i++)
#pragma unroll
        for (int j = 0; j < NJ; j++) {
            int gn = col0 + wc * (BN / WC) + j * 16 + ccol;
            if (gn >= N) continue;
            int gm0 = row0 + wr * 64 + i * 16 + crow;
            float bv = (direct && bias) ? bias[gn] : 0.f;
            if (direct && CBf) {
#pragma unroll
                for (int reg = 0; reg < 4; reg++)
                    CBf[(size_t)(gm0 + reg) * N + gn] = (short)f2bf_rne(acc[i][j][reg] + bv);
            } else {
#pragma unroll
                for (int reg = 0; reg < 4; reg++)
                    Cout[(size_t)(gm0 + reg) * N + gn] = acc[i][j][reg] + bv;
            }
        }
}

// ---------------- fused xproj GEMM (BM=64, BN=64, full coverage) ----------------
__global__ __launch_bounds__(256) void gemm_xproj_kernel(const short* __restrict__ Ah,
                                                         const short* __restrict__ Bh,
                                                         float* __restrict__ projBC,
                                                         short* __restrict__ dtB,
                                                         const float* __restrict__ dtb,
                                                         int M, int K) {
    constexpr int BM = 64, BN = 64, BK = 32;
    constexpr int LDSS = BK + 8;
    constexpr int N = NCMB;
    __shared__ short As[2][BM * LDSS];
    __shared__ short Bs[2][BN * LDSS];

    const int tid = threadIdx.x;
    const int lane = tid & 63;
    const int wc = tid >> 6;
    const int row0 = blockIdx.y * BM, col0 = blockIdx.x * BN;
    const bf16x8 ZV = {0, 0, 0, 0, 0, 0, 0, 0};

    bf16x8 aPh, bPh;
    f32x4 acc[4] = {};

    auto loadG = [&](int k0) {
        int r = tid >> 2, cg = (tid & 3) * 8;
        aPh = *(const bf16x8*)&Ah[(size_t)(row0 + r) * K + k0 + cg];
        int n = col0 + r;
        bPh = (n < N) ? *(const bf16x8*)&Bh[(size_t)n * K + k0 + cg] : ZV;
    };
    auto storeLDS = [&](int p) {
        int r = tid >> 2, cg = (tid & 3) * 8;
        *(bf16x8*)&As[p][r * LDSS + cg] = aPh;
        *(bf16x8*)&Bs[p][r * LDSS + cg] = bPh;
    };
    auto compute = [&](int p) {
        const int fr = lane & 15;
        const int kg = (lane >> 4) * 8;
        bf16x8 aH[4], bH;
#pragma unroll
        for (int i = 0; i < 4; i++)
            aH[i] = *(const bf16x8*)&As[p][(i * 16 + fr) * LDSS + kg];
        bH = *(const bf16x8*)&Bs[p][(wc * 16 + fr) * LDSS + kg];
#pragma unroll
        for (int i = 0; i < 4; i++)
            acc[i] = __builtin_amdgcn_mfma_f32_16x16x32_bf16(aH[i], bH, acc[i], 0, 0, 0);
    };

    loadG(0);
    storeLDS(0);
    __syncthreads();
    int p = 0;
    for (int k0 = BK;; k0 += BK) {
        const bool has_next = (k0 < K);
        if (has_next) loadG(k0);
        compute(p);
        if (!has_next) break;
        storeLDS(p ^ 1);
        __syncthreads();
        p ^= 1;
    }

    const int crow = (lane >> 4) * 4;
    const int ccol = lane & 15;
#pragma unroll
    for (int i = 0; i < 4; i++) {
        int gn = col0 + wc * 16 + ccol;
        if (gn >= NCMB) continue;
        int gm0 = row0 + i * 16 + crow;
        if (gn < 32) {
#pragma unroll
            for (int reg = 0; reg < 4; reg++)
                projBC[(size_t)(gm0 + reg) * 32 + gn] = acc[i][reg];
        } else {
            int d = gn - 32;
            float bv = dtb[d];
#pragma unroll
            for (int reg = 0; reg < 4; reg++) {
                float v = acc[i][reg] + bv;
                v = (v > 20.f) ? v : __logf(1.f + __expf(v));   // softplus
                dtB[(size_t)(gm0 + reg) * DINNER + d] = (short)f2bf_rne(v);
            }
        }
    }
}

// ---------------- split-K reduce (patch embed only) ----------------
__global__ __launch_bounds__(256) void reduce_kernel(const float* __restrict__ parts,
                                                     short* __restrict__ outH,
                                                     const float* __restrict__ bias,
                                                     long MN, int N, int SK) {
    long i = (long)blockIdx.x * 256 + threadIdx.x;
    if (i * 4 >= MN) return;
    float4 acc = *(const float4*)&parts[i * 4];
    for (int z = 1; z < SK; z++) {
        float4 v = *(const float4*)&parts[(size_t)z * MN + i * 4];
        acc.x += v.x; acc.y += v.y; acc.z += v.z; acc.w += v.w;
    }
    if (bias) {
        int col = (int)((i * 4) % N);
        float4 bv = *(const float4*)&bias[col];
        acc.x += bv.x; acc.y += bv.y; acc.z += bv.z; acc.w += bv.w;
    }
    short4 h;
    h.x = (short)f2bf_rne(acc.x);
    h.y = (short)f2bf_rne(acc.y);
    h.z = (short)f2bf_rne(acc.z);
    h.w = (short)f2bf_rne(acc.w);
    *(short4*)&outH[i * 4] = h;
}

// ---------------- causal depthwise conv + SiLU, 4 channels/thread ----------------
__global__ __launch_bounds__(256) void conv_silu_kernel(const short* __restrict__ xzBf,
                                                        const float* __restrict__ cw,
                                                        const float* __restrict__ cb,
                                                        short* __restrict__ xcH) {
    size_t idx = (size_t)blockIdx.x * 256 + threadIdx.x;
    if (idx >= (size_t)RTOT * (DINNER / 4)) return;
    int e0 = (int)(idx % (DINNER / 4)) * 4;
    size_t r = idx / (DINNER / 4);
    int l = (int)(r % NP);
    size_t b = r / NP;
    float acc[4];
    {
        float4 cbv = *(const float4*)&cb[e0];
        acc[0] = cbv.x; acc[1] = cbv.y; acc[2] = cbv.z; acc[3] = cbv.w;
    }
    float4 wv[4];
#pragma unroll
    for (int j = 0; j < 4; j++) wv[j] = *(const float4*)&cw[(e0 + j) * DCONV];
#pragma unroll
    for (int k = 0; k < DCONV; k++) {
        int ls = l + k - (DCONV - 1);
        if (ls >= 0) {
            short4 xv = *(const short4*)&xzBf[(b * NP + ls) * 768 + e0];
            acc[0] += bf2f((unsigned short)xv.x) * (&wv[0].x)[k];
            acc[1] += bf2f((unsigned short)xv.y) * (&wv[1].x)[k];
            acc[2] += bf2f((unsigned short)xv.z) * (&wv[2].x)[k];
            acc[3] += bf2f((unsigned short)xv.w) * (&wv[3].x)[k];
        }
    }
    short4 o;
#pragma unroll
    for (int j = 0; j < 4; j++) {
        float v = acc[j] / (1.f + __expf(-acc[j]));   // silu
        (&o.x)[j] = (short)f2bf_rne(v);
    }
    *(short4*)&xcH[r * DINNER + e0] = o;
}

// ---------------- chunked selective scan ----------------
__global__ __launch_bounds__(128) void scanA_kernel(const short* __restrict__ xcB,
                                                    const float* __restrict__ projBC,
                                                    const short* __restrict__ dtB,
                                                    const float* __restrict__ A_log,
                                                    float* __restrict__ hEnd,
                                                    float* __restrict__ prodDA) {
    int d = blockIdx.x * 128 + threadIdx.x;       // grid.x = 3
    int c = blockIdx.y, b = blockIdx.z;
    float a[DSTATE], h[DSTATE];
#pragma unroll
    for (int s = 0; s < DSTATE; s++) {
        a[s] = -expf(A_log[(size_t)d * DSTATE + s]);   // precise (once per lane)
        h[s] = 0.f;
    }
    const float a0 = a[0];
    bool chain = true;
#pragma unroll
    for (int s = 1; s < DSTATE; s++)
        chain = chain && (fabsf(a[s] - (float)(s + 1) * a0) <= 1e-4f * fabsf(a[s]));
    float sdt = 0.f;
    size_t rbase = (size_t)b * NP + (size_t)c * LC;
    if (chain) {
        for (int l = 0; l < LC; l++) {
            size_t r = rbase + l;
            float dtv = bf2f((unsigned short)dtB[r * DINNER + d]);
            float du = dtv * bf2f((unsigned short)xcB[r * DINNER + d]);
            const float* pb = projBC + r * 32;
            float Bv[DSTATE];
            *(float4*)&Bv[0]  = *(const float4*)&pb[0];
            *(float4*)&Bv[4]  = *(const float4*)&pb[4];
            *(float4*)&Bv[8]  = *(const float4*)&pb[8];
            *(float4*)&Bv[12] = *(const float4*)&pb[12];
            float q = __expf(dtv * a0);
            float dA = q;
            h[0] = h[0] * dA + du * Bv[0];
#pragma unroll
            for (int s = 1; s < DSTATE; s++) {
                dA *= q;
                h[s] = h[s] * dA + du * Bv[s];
            }
            sdt += dtv;
        }
    } else {
        for (int l = 0; l < LC; l++) {
            size_t r = rbase + l;
            float dtv = bf2f((unsigned short)dtB[r * DINNER + d]);
            float du = dtv * bf2f((unsigned short)xcB[r * DINNER + d]);
            const float* pb = projBC + r * 32;
            float Bv[DSTATE];
            *(float4*)&Bv[0]  = *(const float4*)&pb[0];
            *(float4*)&Bv[4]  = *(const float4*)&pb[4];
            *(float4*)&Bv[8]  = *(const float4*)&pb[8];
            *(float4*)&Bv[12] = *(const float4*)&pb[12];
#pragma unroll
            for (int s = 0; s < DSTATE; s++) {
                float dA = __expf(dtv * a[s]);
                h[s] = h[s] * dA + du * Bv[s];
            }
            sdt += dtv;
        }
    }
    float* he = hEnd   + (((size_t)b * CHUNKS + c) * DINNER + d) * DSTATE;
    float* pd = prodDA + (((size_t)b * CHUNKS + c) * DINNER + d) * DSTATE;
#pragma unroll
    for (int g = 0; g < 4; g++)
        *(float4*)&he[g * 4] = *(float4*)&h[g * 4];
    float pv[DSTATE];
#pragma unroll
    for (int s = 0; s < DSTATE; s++) pv[s] = __expf(a[s] * sdt);
#pragma unroll
    for (int g = 0; g < 4; g++)
        *(float4*)&pd[g * 4] = *(float4*)&pv[g * 4];
}

__global__ __launch_bounds__(256) void scanB_kernel(const float* __restrict__ hEnd,
                                                    float* __restrict__ prodDA) {
    int idx = blockIdx.x * 256 + threadIdx.x;
    if (idx >= BB * DINNER * DSTATE) return;
    int b = idx / (DINNER * DSTATE);
    int rem = idx % (DINNER * DSTATE);
    float run = 0.f;
    for (int c = 0; c < CHUNKS; c++) {
        size_t off = ((size_t)b * CHUNKS + c) * (DINNER * DSTATE) + rem;
        float p = prodDA[off];
        float e = hEnd[off];
        prodDA[off] = run;          // hInit for chunk c
        run = run * p + e;
    }
}

// Pass C: rerun from hInit; fused (y+u*D)*silu(z); emits y2 bf16.
__global__ __launch_bounds__(128) void scanC_kernel(const short* __restrict__ xcB,
                                                    const float* __restrict__ projBC,
                                                    const short* __restrict__ dtB,
                                                    const float* __restrict__ hInit,
                                                    const float* __restrict__ A_log,
                                                    const float* __restrict__ Dv,
                                                    const short* __restrict__ xzBf,
                                                    short* __restrict__ yh) {
    int d = blockIdx.x * 128 + threadIdx.x;       // grid.x = 3
    int c = blockIdx.y, b = blockIdx.z;
    float a[DSTATE], h[DSTATE];
#pragma unroll
    for (int s = 0; s < DSTATE; s++)
        a[s] = -expf(A_log[(size_t)d * DSTATE + s]);   // precise (once per lane)
    const float a0 = a[0];
    bool chain = true;
#pragma unroll
    for (int s = 1; s < DSTATE; s++)
        chain = chain && (fabsf(a[s] - (float)(s + 1) * a0) <= 1e-4f * fabsf(a[s]));
    const float* hi = hInit + (((size_t)b * CHUNKS + c) * DINNER + d) * DSTATE;
#pragma unroll
    for (int g = 0; g < 4; g++)
        *(float4*)&h[g * 4] = *(const float4*)&hi[g * 4];
    float Dd = Dv[d];
    size_t rbase = (size_t)b * NP + (size_t)c * LC;
    if (chain) {
        for (int l = 0; l < LC; l++) {
            size_t r = rbase + l;
            float dtv = bf2f((unsigned short)dtB[r * DINNER + d]);
            float u = bf2f((unsigned short)xcB[r * DINNER + d]);
            float du = dtv * u;
            const float* pb = projBC + r * 32;
            float Bv[DSTATE], Cv[DSTATE];
            *(float4*)&Bv[0]  = *(const float4*)&pb[0];
            *(float4*)&Bv[4]  = *(const float4*)&pb[4];
            *(float4*)&Bv[8]  = *(const float4*)&pb[8];
            *(float4*)&Bv[12] = *(const float4*)&pb[12];
            *(float4*)&Cv[0]  = *(const float4*)&pb[16];
            *(float4*)&Cv[4]  = *(const float4*)&pb[20];
            *(float4*)&Cv[8]  = *(const float4*)&pb[24];
            *(float4*)&Cv[12] = *(const float4*)&pb[28];
            float q = __expf(dtv * a0);
            float dA = q;
            h[0] = h[0] * dA + du * Bv[0];
            float y = h[0] * Cv[0];
#pragma unroll
            for (int s = 1; s < DSTATE; s++) {
                dA *= q;
                h[s] = h[s] * dA + du * Bv[s];
                y = fmaf(h[s], Cv[s], y);
            }
            float z = bf2f((unsigned short)xzBf[r * 768 + DINNER + d]);
            float val = (y + u * Dd) * (z / (1.f + __expf(-z)));
            yh[r * DINNER + d] = (short)f2bf_rne(val);
        }
    } else {
        for (int l = 0; l < LC; l++) {
            size_t r = rbase + l;
            float dtv = bf2f((unsigned short)dtB[r * DINNER + d]);
            float u = bf2f((unsigned short)xcB[r * DINNER + d]);
            float du = dtv * u;
            const float* pb = projBC + r * 32;
            float Bv[DSTATE], Cv[DSTATE];
            *(float4*)&Bv[0]  = *(const float4*)&pb[0];
            *(float4*)&Bv[4]  = *(const float4*)&pb[4];
            *(float4*)&Bv[8]  = *(const float4*)&pb[8];
            *(float4*)&Bv[12] = *(const float4*)&pb[12];
            *(float4*)&Cv[0]  = *(const float4*)&pb[16];
            *(float4*)&Cv[4]  = *(const float4*)&pb[20];
            *(float4*)&Cv[8]  = *(const float4*)&pb[24];
            *(float4*)&Cv[12] = *(const float4*)&pb[28];
            float y = 0.f;
#pragma unroll
            for (int s = 0; s < DSTATE; s++) {
                float dA = __expf(dtv * a[s]);
                h[s] = h[s] * dA + du * Bv[s];
                y = fmaf(h[s], Cv[s], y);
            }
            float z = bf2f((unsigned short)xzBf[r * 768 + DINNER + d]);
            float val = (y + u * Dd) * (z / (1.f + __expf(-z)));
            yh[r * DINNER + d] = (short)f2bf_rne(val);
        }
    }
}

// ---------------- final layernorm: per-row stats (bf16 x input) ----------------
__global__ __launch_bounds__(256) void ln_stats_kernel(const short* __restrict__ xh,
                                                       float* __restrict__ stats) {
    int r = blockIdx.x * 4 + (threadIdx.x >> 6);
    int lane = threadIdx.x & 63;
    if (r >= RTOT) return;
    float s = 0.f, ss = 0.f;
    for (int c = lane; c < DM; c += 64) {
        float v = bf2f((unsigned short)xh[(size_t)r * DM + c]);
        s += v;
        ss += v * v;
    }
#pragma unroll
    for (int o = 32; o > 0; o >>= 1) {
        s += __shfl_down(s, o);
        ss += __shfl_down(ss, o);
    }
    if (lane == 0) {
        float mu = s / (float)DM;
        float var = ss / (float)DM - mu * mu;
        stats[r * 2] = mu;
        stats[r * 2 + 1] = rsqrtf(var + 1e-5f);
    }
}

// ---------------- normalized mean over sequence (bf16 x input) ----------------
__global__ __launch_bounds__(256) void ln_mean_kernel(const short* __restrict__ xh,
                                                      const float* __restrict__ stats,
                                                      const float* __restrict__ nw,
                                                      const float* __restrict__ nb,
                                                      float* __restrict__ out) {
    int idx = blockIdx.x * 256 + threadIdx.x;
    if (idx >= BB * DM) return;
    int c = idx % DM;
    int b = idx / DM;
    float acc = 0.f;
    for (int l = 0; l < NP; l++) {
        size_t r = (size_t)b * NP + l;
        float v = bf2f((unsigned short)xh[r * DM + c]);
        acc += (v - stats[r * 2]) * stats[r * 2 + 1];
    }
    out[idx] = acc * (1.f / (float)NP) * nw[c] + nb[c];
}

extern "C" void kernel_launch(void* const* d_in, const int* in_sizes, int n_in,
                              void* d_out, int out_size, void* d_ws, size_t ws_size,
                              hipStream_t stream) {
    const float* img     = (const float*)d_in[0];
    const float* patch_w = (const float*)d_in[1];
    const float* patch_b = (const float*)d_in[2];
    const float* in_w    = (const float*)d_in[3];
    const float* conv_w  = (const float*)d_in[4];
    const float* conv_b  = (const float*)d_in[5];
    const float* xpw     = (const float*)d_in[6];
    const float* dtw     = (const float*)d_in[7];
    const float* dtb     = (const float*)d_in[8];
    const float* A_log   = (const float*)d_in[9];
    const float* Dv      = (const float*)d_in[10];
    const float* outw    = (const float*)d_in[11];
    const float* norm_w  = (const float*)d_in[12];
    const float* norm_b  = (const float*)d_in[13];
    float* out = (float*)d_out;

    float* ws = (float*)d_ws;
    const size_t R = RTOT;
    const size_t SCN = (size_t)BB * CHUNKS * DINNER * DSTATE;   // 5,505,024 fu

    float* xA      = ws;                       // patch-embed x bf16 / final x bf16
    float* xB      = xA + R * DM / 2;
    float* xzB     = xB + R * DM / 2;          // xz bf16 (also im2col col)
    float* xcB     = xzB + R * 768 / 2;        // xc bf16
    float* dtBf    = xcB + R * DINNER / 2;     // dt bf16
    float* projBC  = dtBf + R * DINNER / 2;    // R*32 fp32
    float* scratch = projBC + R * 32;          // 2*SCN shared (patch partials / hEnd+prodDA / y2)
    float* wAll    = scratch + 2 * SCN;        // packed weights
    float* wCrossF = wAll + 4644864;           // 23*768*384 shorts = 3,391,488 fu
    float* stats   = wCrossF + 3391488;        // R*2

    short* wPatch = (short*)wAll;                           // 192*768
    short* wIn    = wPatch + (size_t)DM * 768;              // 24*768*192
    short* wOut   = wIn + (size_t)DEPTH * 2 * DINNER * DM;  // 24*192*384
    short* wCmb   = wOut + (size_t)DEPTH * DM * DINNER;     // 24*416*384
    short* wCross = (short*)wCrossF;                        // 23*768*384

    short* y2h = (short*)scratch;              // y2 bf16 (dead hEnd region)

    // ---- pre-pack weights + combined xproj/dt weight + cross-layer weights ----
    pack_w_kernel<<<dim3((DM * 768 / 4 + 255) / 256), 256, 0, stream>>>(
        patch_w, wPatch, DM * 768);
    pack_w_kernel<<<dim3((DEPTH * 2 * DINNER * DM / 4 + 255) / 256), 256, 0, stream>>>(
        in_w, wIn, DEPTH * 2 * DINNER * DM);
    pack_w_kernel<<<dim3((DEPTH * DM * DINNER / 4 + 255) / 256), 256, 0, stream>>>(
        outw, wOut, DEPTH * DM * DINNER);
    wcmb_kernel<<<dim3((DEPTH * NCMB * DINNER + 255) / 256), 256, 0, stream>>>(
        xpw, dtw, wCmb);
    wcross_kernel<<<dim3(((DEPTH - 1) * 768 * (DINNER / 4) + 255) / 256), 256, 0, stream>>>(
        in_w, outw, wCross);

    // ---- patch embed: bf16 im2col + SK4 GEMM + reduce(+bias) -> bf16 x0 ----
    {
        short* colH = (short*)xzB;
        size_t n = R * 768;
        im2col_pack_kernel<<<dim3((unsigned)((n + 255) / 256)), 256, 0, stream>>>(img, colH);
        gemm_pk_kernel<64, 64><<<dim3(3, RTOT / 64, 4), 256, 0, stream>>>(
            colH, wPatch, scratch, nullptr, nullptr, RTOT, DM, 768, 192);
        long MN = (long)RTOT * DM;
        reduce_kernel<<<dim3((unsigned)((MN / 4 + 255) / 256)), 256, 0, stream>>>(
            scratch, (short*)xA, patch_b, MN, DM, 4);
    }

    short* xzH = (short*)xzB;
    short* xcH = (short*)xcB;
    short* dtH = (short*)dtBf;

    // layer-0 in_proj: xz(bf16) = x0 @ in_w[0]^T   (N=768, K=192)
    gemm_pk_kernel<64, 128><<<dim3(768 / 128, RTOT / 64, 1), 256, 0, stream>>>(
        (short*)xA, wIn, nullptr, xzH, nullptr, RTOT, 2 * DINNER, DM, DM);

    for (int layer = 0; layer < DEPTH; layer++) {
        const float* conv_wl = conv_w + (size_t)layer * DINNER * DCONV;
        const float* conv_bl = conv_b + (size_t)layer * DINNER;
        const float* dtb_l   = dtb + (size_t)layer * DINNER;
        const float* Alog_l  = A_log + (size_t)layer * DINNER * DSTATE;
        const float* Dv_l    = Dv + (size_t)layer * DINNER;
        short* wCmb_l = wCmb + (size_t)layer * NCMB * DINNER;

        // xc(bf16) = silu(causal depthwise conv(xs bf16)) — 4 channels/thread
        {
            size_t n = R * (DINNER / 4);
            conv_silu_kernel<<<dim3((unsigned)((n + 255) / 256)), 256, 0, stream>>>(
                xzH, conv_wl, conv_bl, xcH);
        }
        // fused xproj: [B,C -> projBC fp32 | dt -> softplus bf16]  (N=416, K=384)
        gemm_xproj_kernel<<<dim3(7, RTOT / 64), 256, 0, stream>>>(
            xcH, wCmb_l, projBC, dtH, dtb_l, RTOT, DINNER);
        // chunked scan; scanC emits y2 bf16 into dead hEnd region
        scanA_kernel<<<dim3(3, CHUNKS, BB), 128, 0, stream>>>(
            xcH, projBC, dtH, Alog_l, scratch, scratch + SCN);
        scanB_kernel<<<dim3((BB * DINNER * DSTATE + 255) / 256), 256, 0, stream>>>(
            scratch, scratch + SCN);
        scanC_kernel<<<dim3(3, CHUNKS, BB), 128, 0, stream>>>(
            xcH, projBC, dtH, scratch + SCN, Alog_l, Dv_l, xzH, y2h);
        if (layer < DEPTH - 1) {
            // fused cross-layer: xz_next(bf16) = y2 @ Wcross[layer]^T (N=768, K=384)
            short* wX = wCross + (size_t)layer * 768 * DINNER;
            gemm_pk_kernel<64, 128><<<dim3(768 / 128, RTOT / 64, 1), 256, 0, stream>>>(
                y2h, wX, nullptr, xzH, nullptr, RTOT, 2 * DINNER, DINNER, DINNER);
        } else {
            // final out_proj: x(bf16) = y2 @ outw[23]^T (N=192, K=384)
            short* wOut_l = wOut + (size_t)layer * DM * DINNER;
            gemm_pk_kernel<64, 64><<<dim3(DM / 64, RTOT / 64, 1), 256, 0, stream>>>(
                y2h, wOut_l, nullptr, (short*)xB, nullptr, RTOT, DM, DINNER, DINNER);
        }
    }

    // final layernorm + mean over sequence (bf16 x)
    short* xfH = (short*)xB;
    ln_stats_kernel<<<dim3(RTOT / 4), 256, 0, stream>>>(xfH, stats);
    ln_mean_kernel<<<dim3((BB * DM + 255) / 256), 256, 0, stream>>>(
        xfH, stats, norm_w, norm_b, out);
}

// Round 18
// 2901.483 us; speedup vs baseline: 1.0546x; 1.0546x over previous
//
#include <hip/hip_runtime.h>
#include <hip/hip_bf16.h>
#include <math.h>

#define BB 64
#define IMG 224
#define PP 16
#define CIN 3
#define DM 192
#define DEPTH 24
#define DSTATE 16
#define DINNER 384
#define DTR 12
#define DCONV 4
#define NP 196              // (224/16)^2
#define RTOT (BB * NP)      // 12544 rows
#define CHUNKS 14
#define LC 14               // NP / CHUNKS
#define NCMB (2 * DSTATE + DINNER)   // 416 = B,C (32) + dt (384)

typedef short bf16x8 __attribute__((ext_vector_type(8)));
typedef float f32x4 __attribute__((ext_vector_type(4)));

__device__ inline unsigned short f2bf_rne(float f) {
    unsigned u = __float_as_uint(f);
    unsigned r = u + 0x7fffu + ((u >> 16) & 1u);
    return (unsigned short)(r >> 16);
}
__device__ inline float bf2f(unsigned short s) {
    return __uint_as_float(((unsigned)s) << 16);
}

// ---------------- im2col for patch embed, emitting bf16 ----------------
__global__ __launch_bounds__(256) void im2col_pack_kernel(const float* __restrict__ img,
                                                          short* __restrict__ colH) {
    size_t idx = (size_t)blockIdx.x * 256 + threadIdx.x;
    if (idx >= (size_t)RTOT * 768) return;
    int t = (int)(idx % 768);
    size_t r = idx / 768;
    int l = (int)(r % NP);
    int b = (int)(r / NP);
    int ph = l / 14, pw = l % 14;
    int ci = t / 256, rem = t % 256;
    int i = rem / 16, j = rem % 16;
    float v = img[(((size_t)b * CIN + ci) * IMG + ph * 16 + i) * IMG + pw * 16 + j];
    colH[idx] = (short)f2bf_rne(v);
}

// ---------------- weight pack: fp32[NE] -> bf16 ----------------
__global__ __launch_bounds__(256) void pack_w_kernel(const float* __restrict__ W,
                                                     short* __restrict__ Wh, int NE) {
    int i = blockIdx.x * 256 + threadIdx.x;
    if (i * 4 >= NE) return;
    float4 v = *(const float4*)&W[i * 4];
    short4 h;
    h.x = (short)f2bf_rne(v.x);
    h.y = (short)f2bf_rne(v.y);
    h.z = (short)f2bf_rne(v.z);
    h.w = (short)f2bf_rne(v.w);
    *(short4*)&Wh[i * 4] = h;
}

// ---------------- transpose-pack outw: [DEPTH][DM][DINNER] fp32 -> [DEPTH][DINNER][DM] bf16 ----------------
__global__ __launch_bounds__(256) void packT_out_kernel(const float* __restrict__ outw,
                                                        short* __restrict__ wOutT) {
    int idx = blockIdx.x * 256 + threadIdx.x;
    if (idx >= DEPTH * DM * DINNER) return;
    int layer = idx / (DM * DINNER);
    int rem = idx % (DM * DINNER);
    int m = rem / DINNER;           // coalesced read over k
    int k = rem % DINNER;
    float v = outw[idx];
    wOutT[((size_t)layer * DINNER + k) * DM + m] = (short)f2bf_rne(v);
}

// ---------------- combined xproj weight: [DEPTH][416][384] bf16 ----------------
__global__ __launch_bounds__(256) void wcmb_kernel(const float* __restrict__ xpw,
                                                   const float* __restrict__ dtw,
                                                   short* __restrict__ wCmb) {
    int idx = blockIdx.x * 256 + threadIdx.x;
    if (idx >= DEPTH * NCMB * DINNER) return;
    int layer = idx / (NCMB * DINNER);
    int rem = idx % (NCMB * DINNER);
    int n = rem / DINNER;
    int k = rem % DINNER;
    const float* xp = xpw + (size_t)layer * 44 * DINNER;
    float v;
    if (n < 32) {
        v = xp[(DTR + n) * DINNER + k];
    } else {
        int d = n - 32;
        const float* w = dtw + ((size_t)layer * DINNER + d) * DTR;
        v = 0.f;
#pragma unroll
        for (int j = 0; j < DTR; j++) v += w[j] * xp[j * DINNER + k];
    }
    wCmb[idx] = (short)f2bf_rne(v);
}

// ---------------- batched MFMA wcross: Wcross[l] = Win[l+1] @ WoutT[l]^T ----------------
// A = wIn + (z+1)*768*DM  (768 x 192, row stride 192)
// B = wOutT + z*DINNER*DM (384 x 192, row stride 192)
// C = wCross + z*768*DINNER (bf16, row stride 384). BM=BN=64, K=192, dbuf LDS.
__global__ __launch_bounds__(256) void gemm_wcross_kernel(const short* __restrict__ wIn,
                                                          const short* __restrict__ wOutT,
                                                          short* __restrict__ wCross) {
    constexpr int BK = 32, LDSS = BK + 8, K = DM;
    __shared__ short As[2][64 * LDSS];
    __shared__ short Bs[2][64 * LDSS];
    const int tid = threadIdx.x;
    const int lane = tid & 63;
    const int wc = tid >> 6;                    // 4 waves, 16 cols each
    const int layer = blockIdx.z;
    const short* Ah = wIn + ((size_t)(layer + 1)) * 768 * DM;
    const short* Bh = wOutT + (size_t)layer * DINNER * DM;
    short* Cc = wCross + (size_t)layer * 768 * DINNER;
    const int row0 = blockIdx.y * 64, col0 = blockIdx.x * 64;

    bf16x8 aPh, bPh;
    f32x4 acc[4] = {};

    auto loadG = [&](int k0) {
        int r = tid >> 2, cg = (tid & 3) * 8;
        aPh = *(const bf16x8*)&Ah[(size_t)(row0 + r) * K + k0 + cg];
        bPh = *(const bf16x8*)&Bh[(size_t)(col0 + r) * K + k0 + cg];
    };
    auto storeLDS = [&](int p) {
        int r = tid >> 2, cg = (tid & 3) * 8;
        *(bf16x8*)&As[p][r * LDSS + cg] = aPh;
        *(bf16x8*)&Bs[p][r * LDSS + cg] = bPh;
    };
    auto compute = [&](int p) {
        const int fr = lane & 15;
        const int kg = (lane >> 4) * 8;
        bf16x8 aH[4], bH;
#pragma unroll
        for (int i = 0; i < 4; i++)
            aH[i] = *(const bf16x8*)&As[p][(i * 16 + fr) * LDSS + kg];
        bH = *(const bf16x8*)&Bs[p][(wc * 16 + fr) * LDSS + kg];
#pragma unroll
        for (int i = 0; i < 4; i++)
            acc[i] = __builtin_amdgcn_mfma_f32_16x16x32_bf16(aH[i], bH, acc[i], 0, 0, 0);
    };

    loadG(0);
    storeLDS(0);
    __syncthreads();
    int p = 0;
    for (int k0 = BK;; k0 += BK) {
        const bool has_next = (k0 < K);
        if (has_next) loadG(k0);
        compute(p);
        if (!has_next) break;
        storeLDS(p ^ 1);
        __syncthreads();
        p ^= 1;
    }

    const int crow = (lane >> 4) * 4;
    const int ccol = lane & 15;
#pragma unroll
    for (int i = 0; i < 4; i++) {
        int gn = col0 + wc * 16 + ccol;
        int gm0 = row0 + i * 16 + crow;
#pragma unroll
        for (int reg = 0; reg < 4; reg++)
            Cc[(size_t)(gm0 + reg) * DINNER + gn] = (short)f2bf_rne(acc[i][reg]);
    }
}

// ---------------- bf16 MFMA GEMM, double-buffered LDS, 1 barrier/k-iter ----------------
template<int BM, int BN>
__global__ __launch_bounds__(256) void gemm_pk_kernel(const short* __restrict__ Ah,
                                                      const short* __restrict__ Bh,
                                                      float* __restrict__ C,
                                                      short* __restrict__ CBf,
                                                      const float* __restrict__ bias,
                                                      int M, int N, int K, int Kc) {
    constexpr int BK = 32;
    constexpr int LDSS = BK + 8;
    constexpr int WR = BM / 64;
    constexpr int WC = 4 / WR;
    constexpr int NJ = BN / WC / 16;
    constexpr int A8 = BM / 64;
    constexpr int B8 = BN / 64;
    __shared__ short As[2][BM * LDSS];
    __shared__ short Bs[2][BN * LDSS];

    const int tid = threadIdx.x;
    const int lane = tid & 63;
    const int wid = tid >> 6;
    const int wr = wid / WC, wc = wid % WC;
    const int row0 = blockIdx.y * BM, col0 = blockIdx.x * BN;
    const int kbase = blockIdx.z * Kc;
    const bf16x8 ZV = {0, 0, 0, 0, 0, 0, 0, 0};

    bf16x8 aPh[A8], bPh[B8];
    f32x4 acc[4][NJ] = {};

    auto loadG = [&](int k0) {
#pragma unroll
        for (int i = 0; i < A8; i++) {
            int lin = tid + i * 256;
            int r = lin >> 2, cg = (lin & 3) * 8;
            aPh[i] = *(const bf16x8*)&Ah[(size_t)(row0 + r) * K + k0 + cg];
        }
#pragma unroll
        for (int i = 0; i < B8; i++) {
            int lin = tid + i * 256;
            int r = lin >> 2, cg = (lin & 3) * 8;
            int n = col0 + r;
            bPh[i] = (n < N) ? *(const bf16x8*)&Bh[(size_t)n * K + k0 + cg] : ZV;
        }
    };
    auto storeLDS = [&](int p) {
#pragma unroll
        for (int i = 0; i < A8; i++) {
            int lin = tid + i * 256;
            int r = lin >> 2, cg = (lin & 3) * 8;
            *(bf16x8*)&As[p][r * LDSS + cg] = aPh[i];
        }
#pragma unroll
        for (int i = 0; i < B8; i++) {
            int lin = tid + i * 256;
            int r = lin >> 2, cg = (lin & 3) * 8;
            *(bf16x8*)&Bs[p][r * LDSS + cg] = bPh[i];
        }
    };
    auto compute = [&](int p) {
        const int fr = lane & 15;
        const int kg = (lane >> 4) * 8;
        bf16x8 aH[4], bH[NJ];
#pragma unroll
        for (int i = 0; i < 4; i++)
            aH[i] = *(const bf16x8*)&As[p][(wr * 64 + i * 16 + fr) * LDSS + kg];
#pragma unroll
        for (int j = 0; j < NJ; j++)
            bH[j] = *(const bf16x8*)&Bs[p][(wc * (BN / WC) + j * 16 + fr) * LDSS + kg];
#pragma unroll
        for (int i = 0; i < 4; i++)
#pragma unroll
            for (int j = 0; j < NJ; j++)
                acc[i][j] = __builtin_amdgcn_mfma_f32_16x16x32_bf16(aH[i], bH[j], acc[i][j], 0, 0, 0);
    };

    loadG(kbase);
    storeLDS(0);
    __syncthreads();
    int p = 0;
    for (int k0 = kbase + BK;; k0 += BK) {
        const bool has_next = (k0 < kbase + Kc);
        if (has_next) loadG(k0);
        compute(p);
        if (!has_next) break;
        storeLDS(p ^ 1);
        __syncthreads();
        p ^= 1;
    }

    const bool direct = (gridDim.z == 1);
    float* Cout = C + (size_t)blockIdx.z * M * N;
    const int crow = (lane >> 4) * 4;
    const int ccol = lane & 15;
#pragma unroll
    for (int i = 0; i < 4; i++)
#pragma unroll
        for (int j = 0; j < NJ; j++) {
            int gn = col0 + wc * (BN / WC) + j * 16 + ccol;
            if (gn >= N) continue;
            int gm0 = row0 + wr * 64 + i * 16 + crow;
            float bv = (direct && bias) ? bias[gn] : 0.f;
            if (direct && CBf) {
#pragma unroll
                for (int reg = 0; reg < 4; reg++)
                    CBf[(size_t)(gm0 + reg) * N + gn] = (short)f2bf_rne(acc[i][j][reg] + bv);
            } else {
#pragma unroll
                for (int reg = 0; reg < 4; reg++)
                    Cout[(size_t)(gm0 + reg) * N + gn] = acc[i][j][reg] + bv;
            }
        }
}

// ---------------- fused xproj GEMM (BM=64, BN=64, full coverage) ----------------
__global__ __launch_bounds__(256) void gemm_xproj_kernel(const short* __restrict__ Ah,
                                                         const short* __restrict__ Bh,
                                                         float* __restrict__ projBC,
                                                         short* __restrict__ dtB,
                                                         const float* __restrict__ dtb,
                                                         int M, int K) {
    constexpr int BM = 64, BN = 64, BK = 32;
    constexpr int LDSS = BK + 8;
    constexpr int N = NCMB;
    __shared__ short As[2][BM * LDSS];
    __shared__ short Bs[2][BN * LDSS];

    const int tid = threadIdx.x;
    const int lane = tid & 63;
    const int wc = tid >> 6;
    const int row0 = blockIdx.y * BM, col0 = blockIdx.x * BN;
    const bf16x8 ZV = {0, 0, 0, 0, 0, 0, 0, 0};

    bf16x8 aPh, bPh;
    f32x4 acc[4] = {};

    auto loadG = [&](int k0) {
        int r = tid >> 2, cg = (tid & 3) * 8;
        aPh = *(const bf16x8*)&Ah[(size_t)(row0 + r) * K + k0 + cg];
        int n = col0 + r;
        bPh = (n < N) ? *(const bf16x8*)&Bh[(size_t)n * K + k0 + cg] : ZV;
    };
    auto storeLDS = [&](int p) {
        int r = tid >> 2, cg = (tid & 3) * 8;
        *(bf16x8*)&As[p][r * LDSS + cg] = aPh;
        *(bf16x8*)&Bs[p][r * LDSS + cg] = bPh;
    };
    auto compute = [&](int p) {
        const int fr = lane & 15;
        const int kg = (lane >> 4) * 8;
        bf16x8 aH[4], bH;
#pragma unroll
        for (int i = 0; i < 4; i++)
            aH[i] = *(const bf16x8*)&As[p][(i * 16 + fr) * LDSS + kg];
        bH = *(const bf16x8*)&Bs[p][(wc * 16 + fr) * LDSS + kg];
#pragma unroll
        for (int i = 0; i < 4; i++)
            acc[i] = __builtin_amdgcn_mfma_f32_16x16x32_bf16(aH[i], bH, acc[i], 0, 0, 0);
    };

    loadG(0);
    storeLDS(0);
    __syncthreads();
    int p = 0;
    for (int k0 = BK;; k0 += BK) {
        const bool has_next = (k0 < K);
        if (has_next) loadG(k0);
        compute(p);
        if (!has_next) break;
        storeLDS(p ^ 1);
        __syncthreads();
        p ^= 1;
    }

    const int crow = (lane >> 4) * 4;
    const int ccol = lane & 15;
#pragma unroll
    for (int i = 0; i < 4; i++) {
        int gn = col0 + wc * 16 + ccol;
        if (gn >= NCMB) continue;
        int gm0 = row0 + i * 16 + crow;
        if (gn < 32) {
#pragma unroll
            for (int reg = 0; reg < 4; reg++)
                projBC[(size_t)(gm0 + reg) * 32 + gn] = acc[i][reg];
        } else {
            int d = gn - 32;
            float bv = dtb[d];
#pragma unroll
            for (int reg = 0; reg < 4; reg++) {
                float v = acc[i][reg] + bv;
                v = (v > 20.f) ? v : __logf(1.f + __expf(v));   // softplus
                dtB[(size_t)(gm0 + reg) * DINNER + d] = (short)f2bf_rne(v);
            }
        }
    }
}

// ---------------- split-K reduce (patch embed only) ----------------
__global__ __launch_bounds__(256) void reduce_kernel(const float* __restrict__ parts,
                                                     short* __restrict__ outH,
                                                     const float* __restrict__ bias,
                                                     long MN, int N, int SK) {
    long i = (long)blockIdx.x * 256 + threadIdx.x;
    if (i * 4 >= MN) return;
    float4 acc = *(const float4*)&parts[i * 4];
    for (int z = 1; z < SK; z++) {
        float4 v = *(const float4*)&parts[(size_t)z * MN + i * 4];
        acc.x += v.x; acc.y += v.y; acc.z += v.z; acc.w += v.w;
    }
    if (bias) {
        int col = (int)((i * 4) % N);
        float4 bv = *(const float4*)&bias[col];
        acc.x += bv.x; acc.y += bv.y; acc.z += bv.z; acc.w += bv.w;
    }
    short4 h;
    h.x = (short)f2bf_rne(acc.x);
    h.y = (short)f2bf_rne(acc.y);
    h.z = (short)f2bf_rne(acc.z);
    h.w = (short)f2bf_rne(acc.w);
    *(short4*)&outH[i * 4] = h;
}

// ---------------- causal depthwise conv + SiLU, 4 channels/thread ----------------
__global__ __launch_bounds__(256) void conv_silu_kernel(const short* __restrict__ xzBf,
                                                        const float* __restrict__ cw,
                                                        const float* __restrict__ cb,
                                                        short* __restrict__ xcH) {
    size_t idx = (size_t)blockIdx.x * 256 + threadIdx.x;
    if (idx >= (size_t)RTOT * (DINNER / 4)) return;
    int e0 = (int)(idx % (DINNER / 4)) * 4;
    size_t r = idx / (DINNER / 4);
    int l = (int)(r % NP);
    size_t b = r / NP;
    float acc[4];
    {
        float4 cbv = *(const float4*)&cb[e0];
        acc[0] = cbv.x; acc[1] = cbv.y; acc[2] = cbv.z; acc[3] = cbv.w;
    }
    float4 wv[4];
#pragma unroll
    for (int j = 0; j < 4; j++) wv[j] = *(const float4*)&cw[(e0 + j) * DCONV];
#pragma unroll
    for (int k = 0; k < DCONV; k++) {
        int ls = l + k - (DCONV - 1);
        if (ls >= 0) {
            short4 xv = *(const short4*)&xzBf[(b * NP + ls) * 768 + e0];
            acc[0] += bf2f((unsigned short)xv.x) * (&wv[0].x)[k];
            acc[1] += bf2f((unsigned short)xv.y) * (&wv[1].x)[k];
            acc[2] += bf2f((unsigned short)xv.z) * (&wv[2].x)[k];
            acc[3] += bf2f((unsigned short)xv.w) * (&wv[3].x)[k];
        }
    }
    short4 o;
#pragma unroll
    for (int j = 0; j < 4; j++) {
        float v = acc[j] / (1.f + __expf(-acc[j]));   // silu
        (&o.x)[j] = (short)f2bf_rne(v);
    }
    *(short4*)&xcH[r * DINNER + e0] = o;
}

// ---------------- chunked selective scan ----------------
__global__ __launch_bounds__(128) void scanA_kernel(const short* __restrict__ xcB,
                                                    const float* __restrict__ projBC,
                                                    const short* __restrict__ dtB,
                                                    const float* __restrict__ A_log,
                                                    float* __restrict__ hEnd,
                                                    float* __restrict__ prodDA) {
    int d = blockIdx.x * 128 + threadIdx.x;       // grid.x = 3
    int c = blockIdx.y, b = blockIdx.z;
    float a[DSTATE], h[DSTATE];
#pragma unroll
    for (int s = 0; s < DSTATE; s++) {
        a[s] = -expf(A_log[(size_t)d * DSTATE + s]);   // precise (once per lane)
        h[s] = 0.f;
    }
    const float a0 = a[0];
    bool chain = true;
#pragma unroll
    for (int s = 1; s < DSTATE; s++)
        chain = chain && (fabsf(a[s] - (float)(s + 1) * a0) <= 1e-4f * fabsf(a[s]));
    float sdt = 0.f;
    size_t rbase = (size_t)b * NP + (size_t)c * LC;
    if (chain) {
        for (int l = 0; l < LC; l++) {
            size_t r = rbase + l;
            float dtv = bf2f((unsigned short)dtB[r * DINNER + d]);
            float du = dtv * bf2f((unsigned short)xcB[r * DINNER + d]);
            const float* pb = projBC + r * 32;
            float Bv[DSTATE];
            *(float4*)&Bv[0]  = *(const float4*)&pb[0];
            *(float4*)&Bv[4]  = *(const float4*)&pb[4];
            *(float4*)&Bv[8]  = *(const float4*)&pb[8];
            *(float4*)&Bv[12] = *(const float4*)&pb[12];
            float q = __expf(dtv * a0);
            float dA = q;
            h[0] = h[0] * dA + du * Bv[0];
#pragma unroll
            for (int s = 1; s < DSTATE; s++) {
                dA *= q;
                h[s] = h[s] * dA + du * Bv[s];
            }
            sdt += dtv;
        }
    } else {
        for (int l = 0; l < LC; l++) {
            size_t r = rbase + l;
            float dtv = bf2f((unsigned short)dtB[r * DINNER + d]);
            float du = dtv * bf2f((unsigned short)xcB[r * DINNER + d]);
            const float* pb = projBC + r * 32;
            float Bv[DSTATE];
            *(float4*)&Bv[0]  = *(const float4*)&pb[0];
            *(float4*)&Bv[4]  = *(const float4*)&pb[4];
            *(float4*)&Bv[8]  = *(const float4*)&pb[8];
            *(float4*)&Bv[12] = *(const float4*)&pb[12];
#pragma unroll
            for (int s = 0; s < DSTATE; s++) {
                float dA = __expf(dtv * a[s]);
                h[s] = h[s] * dA + du * Bv[s];
            }
            sdt += dtv;
        }
    }
    float* he = hEnd   + (((size_t)b * CHUNKS + c) * DINNER + d) * DSTATE;
    float* pd = prodDA + (((size_t)b * CHUNKS + c) * DINNER + d) * DSTATE;
#pragma unroll
    for (int g = 0; g < 4; g++)
        *(float4*)&he[g * 4] = *(float4*)&h[g * 4];
    float pv[DSTATE];
#pragma unroll
    for (int s = 0; s < DSTATE; s++) pv[s] = __expf(a[s] * sdt);
#pragma unroll
    for (int g = 0; g < 4; g++)
        *(float4*)&pd[g * 4] = *(float4*)&pv[g * 4];
}

__global__ __launch_bounds__(256) void scanB_kernel(const float* __restrict__ hEnd,
                                                    float* __restrict__ prodDA) {
    int idx = blockIdx.x * 256 + threadIdx.x;
    if (idx >= BB * DINNER * DSTATE) return;
    int b = idx / (DINNER * DSTATE);
    int rem = idx % (DINNER * DSTATE);
    float run = 0.f;
    for (int c = 0; c < CHUNKS; c++) {
        size_t off = ((size_t)b * CHUNKS + c) * (DINNER * DSTATE) + rem;
        float p = prodDA[off];
        float e = hEnd[off];
        prodDA[off] = run;          // hInit for chunk c
        run = run * p + e;
    }
}

// Pass C: rerun from hInit; fused (y+u*D)*silu(z); emits y2 bf16.
__global__ __launch_bounds__(128) void scanC_kernel(const short* __restrict__ xcB,
                                                    const float* __restrict__ projBC,
                                                    const short* __restrict__ dtB,
                                                    const float* __restrict__ hInit,
                                                    const float* __restrict__ A_log,
                                                    const float* __restrict__ Dv,
                                                    const short* __restrict__ xzBf,
                                                    short* __restrict__ yh) {
    int d = blockIdx.x * 128 + threadIdx.x;       // grid.x = 3
    int c = blockIdx.y, b = blockIdx.z;
    float a[DSTATE], h[DSTATE];
#pragma unroll
    for (int s = 0; s < DSTATE; s++)
        a[s] = -expf(A_log[(size_t)d * DSTATE + s]);   // precise (once per lane)
    const float a0 = a[0];
    bool chain = true;
#pragma unroll
    for (int s = 1; s < DSTATE; s++)
        chain = chain && (fabsf(a[s] - (float)(s + 1) * a0) <= 1e-4f * fabsf(a[s]));
    const float* hi = hInit + (((size_t)b * CHUNKS + c) * DINNER + d) * DSTATE;
#pragma unroll
    for (int g = 0; g < 4; g++)
        *(float4*)&h[g * 4] = *(const float4*)&hi[g * 4];
    float Dd = Dv[d];
    size_t rbase = (size_t)b * NP + (size_t)c * LC;
    if (chain) {
        for (int l = 0; l < LC; l++) {
            size_t r = rbase + l;
            float dtv = bf2f((unsigned short)dtB[r * DINNER + d]);
            float u = bf2f((unsigned short)xcB[r * DINNER + d]);
            float du = dtv * u;
            const float* pb = projBC + r * 32;
            float Bv[DSTATE], Cv[DSTATE];
            *(float4*)&Bv[0]  = *(const float4*)&pb[0];
            *(float4*)&Bv[4]  = *(const float4*)&pb[4];
            *(float4*)&Bv[8]  = *(const float4*)&pb[8];
            *(float4*)&Bv[12] = *(const float4*)&pb[12];
            *(float4*)&Cv[0]  = *(const float4*)&pb[16];
            *(float4*)&Cv[4]  = *(const float4*)&pb[20];
            *(float4*)&Cv[8]  = *(const float4*)&pb[24];
            *(float4*)&Cv[12] = *(const float4*)&pb[28];
            float q = __expf(dtv * a0);
            float dA = q;
            h[0] = h[0] * dA + du * Bv[0];
            float y = h[0] * Cv[0];
#pragma unroll
            for (int s = 1; s < DSTATE; s++) {
                dA *= q;
                h[s] = h[s] * dA + du * Bv[s];
                y = fmaf(h[s], Cv[s], y);
            }
            float z = bf2f((unsigned short)xzBf[r * 768 + DINNER + d]);
            float val = (y + u * Dd) * (z / (1.f + __expf(-z)));
            yh[r * DINNER + d] = (short)f2bf_rne(val);
        }
    } else {
        for (int l = 0; l < LC; l++) {
            size_t r = rbase + l;
            float dtv = bf2f((unsigned short)dtB[r * DINNER + d]);
            float u = bf2f((unsigned short)xcB[r * DINNER + d]);
            float du = dtv * u;
            const float* pb = projBC + r * 32;
            float Bv[DSTATE], Cv[DSTATE];
            *(float4*)&Bv[0]  = *(const float4*)&pb[0];
            *(float4*)&Bv[4]  = *(const float4*)&pb[4];
            *(float4*)&Bv[8]  = *(const float4*)&pb[8];
            *(float4*)&Bv[12] = *(const float4*)&pb[12];
            *(float4*)&Cv[0]  = *(const float4*)&pb[16];
            *(float4*)&Cv[4]  = *(const float4*)&pb[20];
            *(float4*)&Cv[8]  = *(const float4*)&pb[24];
            *(float4*)&Cv[12] = *(const float4*)&pb[28];
            float y = 0.f;
#pragma unroll
            for (int s = 0; s < DSTATE; s++) {
                float dA = __expf(dtv * a[s]);
                h[s] = h[s] * dA + du * Bv[s];
                y = fmaf(h[s], Cv[s], y);
            }
            float z = bf2f((unsigned short)xzBf[r * 768 + DINNER + d]);
            float val = (y + u * Dd) * (z / (1.f + __expf(-z)));
            yh[r * DINNER + d] = (short)f2bf_rne(val);
        }
    }
}

// ---------------- final layernorm: per-row stats (bf16 x input) ----------------
__global__ __launch_bounds__(256) void ln_stats_kernel(const short* __restrict__ xh,
                                                       float* __restrict__ stats) {
    int r = blockIdx.x * 4 + (threadIdx.x >> 6);
    int lane = threadIdx.x & 63;
    if (r >= RTOT) return;
    float s = 0.f, ss = 0.f;
    for (int c = lane; c < DM; c += 64) {
        float v = bf2f((unsigned short)xh[(size_t)r * DM + c]);
        s += v;
        ss += v * v;
    }
#pragma unroll
    for (int o = 32; o > 0; o >>= 1) {
        s += __shfl_down(s, o);
        ss += __shfl_down(ss, o);
    }
    if (lane == 0) {
        float mu = s / (float)DM;
        float var = ss / (float)DM - mu * mu;
        stats[r * 2] = mu;
        stats[r * 2 + 1] = rsqrtf(var + 1e-5f);
    }
}

// ---------------- normalized mean over sequence (bf16 x input) ----------------
__global__ __launch_bounds__(256) void ln_mean_kernel(const short* __restrict__ xh,
                                                      const float* __restrict__ stats,
                                                      const float* __restrict__ nw,
                                                      const float* __restrict__ nb,
                                                      float* __restrict__ out) {
    int idx = blockIdx.x * 256 + threadIdx.x;
    if (idx >= BB * DM) return;
    int c = idx % DM;
    int b = idx / DM;
    float acc = 0.f;
    for (int l = 0; l < NP; l++) {
        size_t r = (size_t)b * NP + l;
        float v = bf2f((unsigned short)xh[r * DM + c]);
        acc += (v - stats[r * 2]) * stats[r * 2 + 1];
    }
    out[idx] = acc * (1.f / (float)NP) * nw[c] + nb[c];
}

extern "C" void kernel_launch(void* const* d_in, const int* in_sizes, int n_in,
                              void* d_out, int out_size, void* d_ws, size_t ws_size,
                              hipStream_t stream) {
    const float* img     = (const float*)d_in[0];
    const float* patch_w = (const float*)d_in[1];
    const float* patch_b = (const float*)d_in[2];
    const float* in_w    = (const float*)d_in[3];
    const float* conv_w  = (const float*)d_in[4];
    const float* conv_b  = (const float*)d_in[5];
    const float* xpw     = (const float*)d_in[6];
    const float* dtw     = (const float*)d_in[7];
    const float* dtb     = (const float*)d_in[8];
    const float* A_log   = (const float*)d_in[9];
    const float* Dv      = (const float*)d_in[10];
    const float* outw    = (const float*)d_in[11];
    const float* norm_w  = (const float*)d_in[12];
    const float* norm_b  = (const float*)d_in[13];
    float* out = (float*)d_out;

    float* ws = (float*)d_ws;
    const size_t R = RTOT;
    const size_t SCN = (size_t)BB * CHUNKS * DINNER * DSTATE;   // 5,505,024 fu

    float* xA      = ws;                       // patch-embed x bf16 / final x bf16
    float* xB      = xA + R * DM / 2;
    float* xzB     = xB + R * DM / 2;          // xz bf16 (also im2col col)
    float* xcB     = xzB + R * 768 / 2;        // xc bf16
    float* dtBf    = xcB + R * DINNER / 2;     // dt bf16
    float* projBC  = dtBf + R * DINNER / 2;    // R*32 fp32
    float* scratch = projBC + R * 32;          // 2*SCN shared (wOutT / patch partials / hEnd+prodDA / y2)
    float* wAll    = scratch + 2 * SCN;        // packed weights
    float* wCrossF = wAll + 4644864;           // 23*768*384 shorts = 3,391,488 fu
    float* stats   = wCrossF + 3391488;        // R*2

    short* wPatch = (short*)wAll;                           // 192*768
    short* wIn    = wPatch + (size_t)DM * 768;              // 24*768*192
    short* wOut   = wIn + (size_t)DEPTH * 2 * DINNER * DM;  // 24*192*384
    short* wCmb   = wOut + (size_t)DEPTH * DM * DINNER;     // 24*416*384
    short* wCross = (short*)wCrossF;                        // 23*768*384

    short* y2h = (short*)scratch;              // y2 bf16 (dead hEnd region)
    short* wOutT = (short*)scratch;            // transposed outw bf16 (dead before patch embed)

    // ---- pre-pack weights + combined xproj/dt weight + MFMA cross-layer weights ----
    pack_w_kernel<<<dim3((DM * 768 / 4 + 255) / 256), 256, 0, stream>>>(
        patch_w, wPatch, DM * 768);
    pack_w_kernel<<<dim3((DEPTH * 2 * DINNER * DM / 4 + 255) / 256), 256, 0, stream>>>(
        in_w, wIn, DEPTH * 2 * DINNER * DM);
    pack_w_kernel<<<dim3((DEPTH * DM * DINNER / 4 + 255) / 256), 256, 0, stream>>>(
        outw, wOut, DEPTH * DM * DINNER);
    wcmb_kernel<<<dim3((DEPTH * NCMB * DINNER + 255) / 256), 256, 0, stream>>>(
        xpw, dtw, wCmb);
    // Wcross via MFMA: transpose-pack outw (into scratch) then batched GEMM
    packT_out_kernel<<<dim3((DEPTH * DM * DINNER + 255) / 256), 256, 0, stream>>>(
        outw, wOutT);
    gemm_wcross_kernel<<<dim3(DINNER / 64, 768 / 64, DEPTH - 1), 256, 0, stream>>>(
        wIn, wOutT, wCross);

    // ---- patch embed: bf16 im2col + SK4 GEMM + reduce(+bias) -> bf16 x0 ----
    {
        short* colH = (short*)xzB;
        size_t n = R * 768;
        im2col_pack_kernel<<<dim3((unsigned)((n + 255) / 256)), 256, 0, stream>>>(img, colH);
        gemm_pk_kernel<64, 64><<<dim3(3, RTOT / 64, 4), 256, 0, stream>>>(
            colH, wPatch, scratch, nullptr, nullptr, RTOT, DM, 768, 192);
        long MN = (long)RTOT * DM;
        reduce_kernel<<<dim3((unsigned)((MN / 4 + 255) / 256)), 256, 0, stream>>>(
            scratch, (short*)xA, patch_b, MN, DM, 4);
    }

    short* xzH = (short*)xzB;
    short* xcH = (short*)xcB;
    short* dtH = (short*)dtBf;

    // layer-0 in_proj: xz(bf16) = x0 @ in_w[0]^T   (N=768, K=192)
    gemm_pk_kernel<64, 128><<<dim3(768 / 128, RTOT / 64, 1), 256, 0, stream>>>(
        (short*)xA, wIn, nullptr, xzH, nullptr, RTOT, 2 * DINNER, DM, DM);

    for (int layer = 0; layer < DEPTH; layer++) {
        const float* conv_wl = conv_w + (size_t)layer * DINNER * DCONV;
        const float* conv_bl = conv_b + (size_t)layer * DINNER;
        const float* dtb_l   = dtb + (size_t)layer * DINNER;
        const float* Alog_l  = A_log + (size_t)layer * DINNER * DSTATE;
        const float* Dv_l    = Dv + (size_t)layer * DINNER;
        short* wCmb_l = wCmb + (size_t)layer * NCMB * DINNER;

        // xc(bf16) = silu(causal depthwise conv(xs bf16)) — 4 channels/thread
        {
            size_t n = R * (DINNER / 4);
            conv_silu_kernel<<<dim3((unsigned)((n + 255) / 256)), 256, 0, stream>>>(
                xzH, conv_wl, conv_bl, xcH);
        }
        // fused xproj: [B,C -> projBC fp32 | dt -> softplus bf16]  (N=416, K=384)
        gemm_xproj_kernel<<<dim3(7, RTOT / 64), 256, 0, stream>>>(
            xcH, wCmb_l, projBC, dtH, dtb_l, RTOT, DINNER);
        // chunked scan; scanC emits y2 bf16 into dead hEnd region
        scanA_kernel<<<dim3(3, CHUNKS, BB), 128, 0, stream>>>(
            xcH, projBC, dtH, Alog_l, scratch, scratch + SCN);
        scanB_kernel<<<dim3((BB * DINNER * DSTATE + 255) / 256), 256, 0, stream>>>(
            scratch, scratch + SCN);
        scanC_kernel<<<dim3(3, CHUNKS, BB), 128, 0, stream>>>(
            xcH, projBC, dtH, scratch + SCN, Alog_l, Dv_l, xzH, y2h);
        if (layer < DEPTH - 1) {
            // fused cross-layer: xz_next(bf16) = y2 @ Wcross[layer]^T (N=768, K=384)
            short* wX = wCross + (size_t)layer * 768 * DINNER;
            gemm_pk_kernel<64, 128><<<dim3(768 / 128, RTOT / 64, 1), 256, 0, stream>>>(
                y2h, wX, nullptr, xzH, nullptr, RTOT, 2 * DINNER, DINNER, DINNER);
        } else {
            // final out_proj: x(bf16) = y2 @ outw[23]^T (N=192, K=384)
            short* wOut_l = wOut + (size_t)layer * DM * DINNER;
            gemm_pk_kernel<64, 64><<<dim3(DM / 64, RTOT / 64, 1), 256, 0, stream>>>(
                y2h, wOut_l, nullptr, (short*)xB, nullptr, RTOT, DM, DINNER, DINNER);
        }
    }

    // final layernorm + mean over sequence (bf16 x)
    short* xfH = (short*)xB;
    ln_stats_kernel<<<dim3(RTOT / 4), 256, 0, stream>>>(xfH, stats);
    ln_mean_kernel<<<dim3((BB * DM + 255) / 256), 256, 0, stream>>>(
        xfH, stats, norm_w, norm_b, out);
}

// Round 19
// 2567.993 us; speedup vs baseline: 1.1915x; 1.1299x over previous
//
#include <hip/hip_runtime.h>
#include <hip/hip_bf16.h>
#include <math.h>

#define BB 64
#define IMG 224
#define PP 16
#define CIN 3
#define DM 192
#define DEPTH 24
#define DSTATE 16
#define DINNER 384
#define DTR 12
#define DCONV 4
#define NP 196              // (224/16)^2
#define RTOT (BB * NP)      // 12544 rows
#define CHUNKS 14
#define LC 14               // NP / CHUNKS
#define NCMB (2 * DSTATE + DINNER)   // 416 = B,C (32) + dt (384)

typedef short bf16x8 __attribute__((ext_vector_type(8)));
typedef float f32x4 __attribute__((ext_vector_type(4)));

__device__ inline unsigned short f2bf_rne(float f) {
    unsigned u = __float_as_uint(f);
    unsigned r = u + 0x7fffu + ((u >> 16) & 1u);
    return (unsigned short)(r >> 16);
}
__device__ inline float bf2f(unsigned short s) {
    return __uint_as_float(((unsigned)s) << 16);
}

// ---------------- im2col for patch embed, emitting bf16 ----------------
__global__ __launch_bounds__(256) void im2col_pack_kernel(const float* __restrict__ img,
                                                          short* __restrict__ colH) {
    size_t idx = (size_t)blockIdx.x * 256 + threadIdx.x;
    if (idx >= (size_t)RTOT * 768) return;
    int t = (int)(idx % 768);
    size_t r = idx / 768;
    int l = (int)(r % NP);
    int b = (int)(r / NP);
    int ph = l / 14, pw = l % 14;
    int ci = t / 256, rem = t % 256;
    int i = rem / 16, j = rem % 16;
    float v = img[(((size_t)b * CIN + ci) * IMG + ph * 16 + i) * IMG + pw * 16 + j];
    colH[idx] = (short)f2bf_rne(v);
}

// ---------------- weight pack: fp32[NE] -> bf16 ----------------
__global__ __launch_bounds__(256) void pack_w_kernel(const float* __restrict__ W,
                                                     short* __restrict__ Wh, int NE) {
    int i = blockIdx.x * 256 + threadIdx.x;
    if (i * 4 >= NE) return;
    float4 v = *(const float4*)&W[i * 4];
    short4 h;
    h.x = (short)f2bf_rne(v.x);
    h.y = (short)f2bf_rne(v.y);
    h.z = (short)f2bf_rne(v.z);
    h.w = (short)f2bf_rne(v.w);
    *(short4*)&Wh[i * 4] = h;
}

// ---------------- transpose-pack outw: [DEPTH][DM][DINNER] fp32 -> [DEPTH][DINNER][DM] bf16 ----------------
__global__ __launch_bounds__(256) void packT_out_kernel(const float* __restrict__ outw,
                                                        short* __restrict__ wOutT) {
    int idx = blockIdx.x * 256 + threadIdx.x;
    if (idx >= DEPTH * DM * DINNER) return;
    int layer = idx / (DM * DINNER);
    int rem = idx % (DM * DINNER);
    int m = rem / DINNER;           // coalesced read over k
    int k = rem % DINNER;
    float v = outw[idx];
    wOutT[((size_t)layer * DINNER + k) * DM + m] = (short)f2bf_rne(v);
}

// ---------------- combined xproj weight: [DEPTH][416][384] bf16 ----------------
__global__ __launch_bounds__(256) void wcmb_kernel(const float* __restrict__ xpw,
                                                   const float* __restrict__ dtw,
                                                   short* __restrict__ wCmb) {
    int idx = blockIdx.x * 256 + threadIdx.x;
    if (idx >= DEPTH * NCMB * DINNER) return;
    int layer = idx / (NCMB * DINNER);
    int rem = idx % (NCMB * DINNER);
    int n = rem / DINNER;
    int k = rem % DINNER;
    const float* xp = xpw + (size_t)layer * 44 * DINNER;
    float v;
    if (n < 32) {
        v = xp[(DTR + n) * DINNER + k];
    } else {
        int d = n - 32;
        const float* w = dtw + ((size_t)layer * DINNER + d) * DTR;
        v = 0.f;
#pragma unroll
        for (int j = 0; j < DTR; j++) v += w[j] * xp[j * DINNER + k];
    }
    wCmb[idx] = (short)f2bf_rne(v);
}

// ---------------- batched MFMA wcross: Wcross[l] = Win[l+1] @ WoutT[l]^T ----------------
__global__ __launch_bounds__(256) void gemm_wcross_kernel(const short* __restrict__ wIn,
                                                          const short* __restrict__ wOutT,
                                                          short* __restrict__ wCross) {
    constexpr int BK = 32, LDSS = BK + 8, K = DM;
    __shared__ short As[2][64 * LDSS];
    __shared__ short Bs[2][64 * LDSS];
    const int tid = threadIdx.x;
    const int lane = tid & 63;
    const int wc = tid >> 6;                    // 4 waves, 16 cols each
    const int layer = blockIdx.z;
    const short* Ah = wIn + ((size_t)(layer + 1)) * 768 * DM;
    const short* Bh = wOutT + (size_t)layer * DINNER * DM;
    short* Cc = wCross + (size_t)layer * 768 * DINNER;
    const int row0 = blockIdx.y * 64, col0 = blockIdx.x * 64;

    bf16x8 aPh, bPh;
    f32x4 acc[4] = {};

    auto loadG = [&](int k0) {
        int r = tid >> 2, cg = (tid & 3) * 8;
        aPh = *(const bf16x8*)&Ah[(size_t)(row0 + r) * K + k0 + cg];
        bPh = *(const bf16x8*)&Bh[(size_t)(col0 + r) * K + k0 + cg];
    };
    auto storeLDS = [&](int p) {
        int r = tid >> 2, cg = (tid & 3) * 8;
        *(bf16x8*)&As[p][r * LDSS + cg] = aPh;
        *(bf16x8*)&Bs[p][r * LDSS + cg] = bPh;
    };
    auto compute = [&](int p) {
        const int fr = lane & 15;
        const int kg = (lane >> 4) * 8;
        bf16x8 aH[4], bH;
#pragma unroll
        for (int i = 0; i < 4; i++)
            aH[i] = *(const bf16x8*)&As[p][(i * 16 + fr) * LDSS + kg];
        bH = *(const bf16x8*)&Bs[p][(wc * 16 + fr) * LDSS + kg];
#pragma unroll
        for (int i = 0; i < 4; i++)
            acc[i] = __builtin_amdgcn_mfma_f32_16x16x32_bf16(aH[i], bH, acc[i], 0, 0, 0);
    };

    loadG(0);
    storeLDS(0);
    __syncthreads();
    int p = 0;
    for (int k0 = BK;; k0 += BK) {
        const bool has_next = (k0 < K);
        if (has_next) loadG(k0);
        compute(p);
        if (!has_next) break;
        storeLDS(p ^ 1);
        __syncthreads();
        p ^= 1;
    }

    const int crow = (lane >> 4) * 4;
    const int ccol = lane & 15;
#pragma unroll
    for (int i = 0; i < 4; i++) {
        int gn = col0 + wc * 16 + ccol;
        int gm0 = row0 + i * 16 + crow;
#pragma unroll
        for (int reg = 0; reg < 4; reg++)
            Cc[(size_t)(gm0 + reg) * DINNER + gn] = (short)f2bf_rne(acc[i][reg]);
    }
}

// ---------------- bf16 MFMA GEMM, double-buffered LDS, 1 barrier/k-iter ----------------
template<int BM, int BN>
__global__ __launch_bounds__(256) void gemm_pk_kernel(const short* __restrict__ Ah,
                                                      const short* __restrict__ Bh,
                                                      float* __restrict__ C,
                                                      short* __restrict__ CBf,
                                                      const float* __restrict__ bias,
                                                      int M, int N, int K, int Kc) {
    constexpr int BK = 32;
    constexpr int LDSS = BK + 8;
    constexpr int WR = BM / 64;
    constexpr int WC = 4 / WR;
    constexpr int NJ = BN / WC / 16;
    constexpr int A8 = BM / 64;
    constexpr int B8 = BN / 64;
    __shared__ short As[2][BM * LDSS];
    __shared__ short Bs[2][BN * LDSS];

    const int tid = threadIdx.x;
    const int lane = tid & 63;
    const int wid = tid >> 6;
    const int wr = wid / WC, wc = wid % WC;
    const int row0 = blockIdx.y * BM, col0 = blockIdx.x * BN;
    const int kbase = blockIdx.z * Kc;
    const bf16x8 ZV = {0, 0, 0, 0, 0, 0, 0, 0};

    bf16x8 aPh[A8], bPh[B8];
    f32x4 acc[4][NJ] = {};

    auto loadG = [&](int k0) {
#pragma unroll
        for (int i = 0; i < A8; i++) {
            int lin = tid + i * 256;
            int r = lin >> 2, cg = (lin & 3) * 8;
            aPh[i] = *(const bf16x8*)&Ah[(size_t)(row0 + r) * K + k0 + cg];
        }
#pragma unroll
        for (int i = 0; i < B8; i++) {
            int lin = tid + i * 256;
            int r = lin >> 2, cg = (lin & 3) * 8;
            int n = col0 + r;
            bPh[i] = (n < N) ? *(const bf16x8*)&Bh[(size_t)n * K + k0 + cg] : ZV;
        }
    };
    auto storeLDS = [&](int p) {
#pragma unroll
        for (int i = 0; i < A8; i++) {
            int lin = tid + i * 256;
            int r = lin >> 2, cg = (lin & 3) * 8;
            *(bf16x8*)&As[p][r * LDSS + cg] = aPh[i];
        }
#pragma unroll
        for (int i = 0; i < B8; i++) {
            int lin = tid + i * 256;
            int r = lin >> 2, cg = (lin & 3) * 8;
            *(bf16x8*)&Bs[p][r * LDSS + cg] = bPh[i];
        }
    };
    auto compute = [&](int p) {
        const int fr = lane & 15;
        const int kg = (lane >> 4) * 8;
        bf16x8 aH[4], bH[NJ];
#pragma unroll
        for (int i = 0; i < 4; i++)
            aH[i] = *(const bf16x8*)&As[p][(wr * 64 + i * 16 + fr) * LDSS + kg];
#pragma unroll
        for (int j = 0; j < NJ; j++)
            bH[j] = *(const bf16x8*)&Bs[p][(wc * (BN / WC) + j * 16 + fr) * LDSS + kg];
#pragma unroll
        for (int i = 0; i < 4; i++)
#pragma unroll
            for (int j = 0; j < NJ; j++)
                acc[i][j] = __builtin_amdgcn_mfma_f32_16x16x32_bf16(aH[i], bH[j], acc[i][j], 0, 0, 0);
    };

    loadG(kbase);
    storeLDS(0);
    __syncthreads();
    int p = 0;
    for (int k0 = kbase + BK;; k0 += BK) {
        const bool has_next = (k0 < kbase + Kc);
        if (has_next) loadG(k0);
        compute(p);
        if (!has_next) break;
        storeLDS(p ^ 1);
        __syncthreads();
        p ^= 1;
    }

    const bool direct = (gridDim.z == 1);
    float* Cout = C + (size_t)blockIdx.z * M * N;
    const int crow = (lane >> 4) * 4;
    const int ccol = lane & 15;
#pragma unroll
    for (int i = 0; i < 4; i++)
#pragma unroll
        for (int j = 0; j < NJ; j++) {
            int gn = col0 + wc * (BN / WC) + j * 16 + ccol;
            if (gn >= N) continue;
            int gm0 = row0 + wr * 64 + i * 16 + crow;
            float bv = (direct && bias) ? bias[gn] : 0.f;
            if (direct && CBf) {
#pragma unroll
                for (int reg = 0; reg < 4; reg++)
                    CBf[(size_t)(gm0 + reg) * N + gn] = (short)f2bf_rne(acc[i][j][reg] + bv);
            } else {
#pragma unroll
                for (int reg = 0; reg < 4; reg++)
                    Cout[(size_t)(gm0 + reg) * N + gn] = acc[i][j][reg] + bv;
            }
        }
}

// ---------------- fused xproj GEMM (BM=64, BN=64, full coverage) ----------------
__global__ __launch_bounds__(256) void gemm_xproj_kernel(const short* __restrict__ Ah,
                                                         const short* __restrict__ Bh,
                                                         float* __restrict__ projBC,
                                                         short* __restrict__ dtB,
                                                         const float* __restrict__ dtb,
                                                         int M, int K) {
    constexpr int BM = 64, BN = 64, BK = 32;
    constexpr int LDSS = BK + 8;
    constexpr int N = NCMB;
    __shared__ short As[2][BM * LDSS];
    __shared__ short Bs[2][BN * LDSS];

    const int tid = threadIdx.x;
    const int lane = tid & 63;
    const int wc = tid >> 6;
    const int row0 = blockIdx.y * BM, col0 = blockIdx.x * BN;
    const bf16x8 ZV = {0, 0, 0, 0, 0, 0, 0, 0};

    bf16x8 aPh, bPh;
    f32x4 acc[4] = {};

    auto loadG = [&](int k0) {
        int r = tid >> 2, cg = (tid & 3) * 8;
        aPh = *(const bf16x8*)&Ah[(size_t)(row0 + r) * K + k0 + cg];
        int n = col0 + r;
        bPh = (n < N) ? *(const bf16x8*)&Bh[(size_t)n * K + k0 + cg] : ZV;
    };
    auto storeLDS = [&](int p) {
        int r = tid >> 2, cg = (tid & 3) * 8;
        *(bf16x8*)&As[p][r * LDSS + cg] = aPh;
        *(bf16x8*)&Bs[p][r * LDSS + cg] = bPh;
    };
    auto compute = [&](int p) {
        const int fr = lane & 15;
        const int kg = (lane >> 4) * 8;
        bf16x8 aH[4], bH;
#pragma unroll
        for (int i = 0; i < 4; i++)
            aH[i] = *(const bf16x8*)&As[p][(i * 16 + fr) * LDSS + kg];
        bH = *(const bf16x8*)&Bs[p][(wc * 16 + fr) * LDSS + kg];
#pragma unroll
        for (int i = 0; i < 4; i++)
            acc[i] = __builtin_amdgcn_mfma_f32_16x16x32_bf16(aH[i], bH, acc[i], 0, 0, 0);
    };

    loadG(0);
    storeLDS(0);
    __syncthreads();
    int p = 0;
    for (int k0 = BK;; k0 += BK) {
        const bool has_next = (k0 < K);
        if (has_next) loadG(k0);
        compute(p);
        if (!has_next) break;
        storeLDS(p ^ 1);
        __syncthreads();
        p ^= 1;
    }

    const int crow = (lane >> 4) * 4;
    const int ccol = lane & 15;
#pragma unroll
    for (int i = 0; i < 4; i++) {
        int gn = col0 + wc * 16 + ccol;
        if (gn >= NCMB) continue;
        int gm0 = row0 + i * 16 + crow;
        if (gn < 32) {
#pragma unroll
            for (int reg = 0; reg < 4; reg++)
                projBC[(size_t)(gm0 + reg) * 32 + gn] = acc[i][reg];
        } else {
            int d = gn - 32;
            float bv = dtb[d];
#pragma unroll
            for (int reg = 0; reg < 4; reg++) {
                float v = acc[i][reg] + bv;
                v = (v > 20.f) ? v : __logf(1.f + __expf(v));   // softplus
                dtB[(size_t)(gm0 + reg) * DINNER + d] = (short)f2bf_rne(v);
            }
        }
    }
}

// ---------------- split-K reduce (patch embed only) ----------------
__global__ __launch_bounds__(256) void reduce_kernel(const float* __restrict__ parts,
                                                     short* __restrict__ outH,
                                                     const float* __restrict__ bias,
                                                     long MN, int N, int SK) {
    long i = (long)blockIdx.x * 256 + threadIdx.x;
    if (i * 4 >= MN) return;
    float4 acc = *(const float4*)&parts[i * 4];
    for (int z = 1; z < SK; z++) {
        float4 v = *(const float4*)&parts[(size_t)z * MN + i * 4];
        acc.x += v.x; acc.y += v.y; acc.z += v.z; acc.w += v.w;
    }
    if (bias) {
        int col = (int)((i * 4) % N);
        float4 bv = *(const float4*)&bias[col];
        acc.x += bv.x; acc.y += bv.y; acc.z += bv.z; acc.w += bv.w;
    }
    short4 h;
    h.x = (short)f2bf_rne(acc.x);
    h.y = (short)f2bf_rne(acc.y);
    h.z = (short)f2bf_rne(acc.z);
    h.w = (short)f2bf_rne(acc.w);
    *(short4*)&outH[i * 4] = h;
}

// ---------------- causal depthwise conv + SiLU, 4 channels/thread ----------------
__global__ __launch_bounds__(256) void conv_silu_kernel(const short* __restrict__ xzBf,
                                                        const float* __restrict__ cw,
                                                        const float* __restrict__ cb,
                                                        short* __restrict__ xcH) {
    size_t idx = (size_t)blockIdx.x * 256 + threadIdx.x;
    if (idx >= (size_t)RTOT * (DINNER / 4)) return;
    int e0 = (int)(idx % (DINNER / 4)) * 4;
    size_t r = idx / (DINNER / 4);
    int l = (int)(r % NP);
    size_t b = r / NP;
    float acc[4];
    {
        float4 cbv = *(const float4*)&cb[e0];
        acc[0] = cbv.x; acc[1] = cbv.y; acc[2] = cbv.z; acc[3] = cbv.w;
    }
    float4 wv[4];
#pragma unroll
    for (int j = 0; j < 4; j++) wv[j] = *(const float4*)&cw[(e0 + j) * DCONV];
#pragma unroll
    for (int k = 0; k < DCONV; k++) {
        int ls = l + k - (DCONV - 1);
        if (ls >= 0) {
            short4 xv = *(const short4*)&xzBf[(b * NP + ls) * 768 + e0];
            acc[0] += bf2f((unsigned short)xv.x) * (&wv[0].x)[k];
            acc[1] += bf2f((unsigned short)xv.y) * (&wv[1].x)[k];
            acc[2] += bf2f((unsigned short)xv.z) * (&wv[2].x)[k];
            acc[3] += bf2f((unsigned short)xv.w) * (&wv[3].x)[k];
        }
    }
    short4 o;
#pragma unroll
    for (int j = 0; j < 4; j++) {
        float v = acc[j] / (1.f + __expf(-acc[j]));   // silu
        (&o.x)[j] = (short)f2bf_rne(v);
    }
    *(short4*)&xcH[r * DINNER + e0] = o;
}

// ---------------- chunked selective scan ----------------
// Pass A: local scan from h=0; stores hEnd (bf16) and per-chunk sum(dt) (fp32).
__global__ __launch_bounds__(128) void scanA_kernel(const short* __restrict__ xcB,
                                                    const float* __restrict__ projBC,
                                                    const short* __restrict__ dtB,
                                                    const float* __restrict__ A_log,
                                                    short* __restrict__ hEndB,
                                                    float* __restrict__ sdtBuf) {
    int d = blockIdx.x * 128 + threadIdx.x;       // grid.x = 3
    int c = blockIdx.y, b = blockIdx.z;
    float a[DSTATE], h[DSTATE];
#pragma unroll
    for (int s = 0; s < DSTATE; s++) {
        a[s] = -expf(A_log[(size_t)d * DSTATE + s]);   // precise (once per lane)
        h[s] = 0.f;
    }
    const float a0 = a[0];
    bool chain = true;
#pragma unroll
    for (int s = 1; s < DSTATE; s++)
        chain = chain && (fabsf(a[s] - (float)(s + 1) * a0) <= 1e-4f * fabsf(a[s]));
    float sdt = 0.f;
    size_t rbase = (size_t)b * NP + (size_t)c * LC;
    if (chain) {
        for (int l = 0; l < LC; l++) {
            size_t r = rbase + l;
            float dtv = bf2f((unsigned short)dtB[r * DINNER + d]);
            float du = dtv * bf2f((unsigned short)xcB[r * DINNER + d]);
            const float* pb = projBC + r * 32;
            float Bv[DSTATE];
            *(float4*)&Bv[0]  = *(const float4*)&pb[0];
            *(float4*)&Bv[4]  = *(const float4*)&pb[4];
            *(float4*)&Bv[8]  = *(const float4*)&pb[8];
            *(float4*)&Bv[12] = *(const float4*)&pb[12];
            float q = __expf(dtv * a0);
            float dA = q;
            h[0] = h[0] * dA + du * Bv[0];
#pragma unroll
            for (int s = 1; s < DSTATE; s++) {
                dA *= q;
                h[s] = h[s] * dA + du * Bv[s];
            }
            sdt += dtv;
        }
    } else {
        for (int l = 0; l < LC; l++) {
            size_t r = rbase + l;
            float dtv = bf2f((unsigned short)dtB[r * DINNER + d]);
            float du = dtv * bf2f((unsigned short)xcB[r * DINNER + d]);
            const float* pb = projBC + r * 32;
            float Bv[DSTATE];
            *(float4*)&Bv[0]  = *(const float4*)&pb[0];
            *(float4*)&Bv[4]  = *(const float4*)&pb[4];
            *(float4*)&Bv[8]  = *(const float4*)&pb[8];
            *(float4*)&Bv[12] = *(const float4*)&pb[12];
#pragma unroll
            for (int s = 0; s < DSTATE; s++) {
                float dA = __expf(dtv * a[s]);
                h[s] = h[s] * dA + du * Bv[s];
            }
            sdt += dtv;
        }
    }
    short* he = hEndB + (((size_t)b * CHUNKS + c) * DINNER + d) * DSTATE;
#pragma unroll
    for (int g = 0; g < 4; g++) {
        short4 o;
        o.x = (short)f2bf_rne(h[g * 4 + 0]);
        o.y = (short)f2bf_rne(h[g * 4 + 1]);
        o.z = (short)f2bf_rne(h[g * 4 + 2]);
        o.w = (short)f2bf_rne(h[g * 4 + 3]);
        *(short4*)&he[g * 4] = o;
    }
    sdtBuf[((size_t)b * CHUNKS + c) * DINNER + d] = sdt;
}

// Pass B: sequential combine over chunks; p reconstructed as exp(a*sdt); bf16 I/O.
__global__ __launch_bounds__(256) void scanB_kernel(const short* __restrict__ hEndB,
                                                    const float* __restrict__ sdtBuf,
                                                    const float* __restrict__ A_log,
                                                    short* __restrict__ hInitB) {
    int idx = blockIdx.x * 256 + threadIdx.x;
    if (idx >= BB * DINNER * DSTATE) return;
    int b = idx / (DINNER * DSTATE);
    int rem = idx % (DINNER * DSTATE);
    int d = rem / DSTATE;
    int s = rem % DSTATE;
    float a = -expf(A_log[(size_t)d * DSTATE + s]);
    float run = 0.f;
    for (int c = 0; c < CHUNKS; c++) {
        size_t off = ((size_t)b * CHUNKS + c) * (DINNER * DSTATE) + rem;
        float p = __expf(a * sdtBuf[((size_t)b * CHUNKS + c) * DINNER + d]);
        float e = bf2f((unsigned short)hEndB[off]);
        hInitB[off] = (short)f2bf_rne(run);
        run = run * p + e;
    }
}

// Pass C: rerun from hInit (bf16); fused (y+u*D)*silu(z); emits y2 bf16.
__global__ __launch_bounds__(128) void scanC_kernel(const short* __restrict__ xcB,
                                                    const float* __restrict__ projBC,
                                                    const short* __restrict__ dtB,
                                                    const short* __restrict__ hInitB,
                                                    const float* __restrict__ A_log,
                                                    const float* __restrict__ Dv,
                                                    const short* __restrict__ xzBf,
                                                    short* __restrict__ yh) {
    int d = blockIdx.x * 128 + threadIdx.x;       // grid.x = 3
    int c = blockIdx.y, b = blockIdx.z;
    float a[DSTATE], h[DSTATE];
#pragma unroll
    for (int s = 0; s < DSTATE; s++)
        a[s] = -expf(A_log[(size_t)d * DSTATE + s]);   // precise (once per lane)
    const float a0 = a[0];
    bool chain = true;
#pragma unroll
    for (int s = 1; s < DSTATE; s++)
        chain = chain && (fabsf(a[s] - (float)(s + 1) * a0) <= 1e-4f * fabsf(a[s]));
    const short* hi = hInitB + (((size_t)b * CHUNKS + c) * DINNER + d) * DSTATE;
#pragma unroll
    for (int g = 0; g < 4; g++) {
        short4 v = *(const short4*)&hi[g * 4];
        h[g * 4 + 0] = bf2f((unsigned short)v.x);
        h[g * 4 + 1] = bf2f((unsigned short)v.y);
        h[g * 4 + 2] = bf2f((unsigned short)v.z);
        h[g * 4 + 3] = bf2f((unsigned short)v.w);
    }
    float Dd = Dv[d];
    size_t rbase = (size_t)b * NP + (size_t)c * LC;
    if (chain) {
        for (int l = 0; l < LC; l++) {
            size_t r = rbase + l;
            float dtv = bf2f((unsigned short)dtB[r * DINNER + d]);
            float u = bf2f((unsigned short)xcB[r * DINNER + d]);
            float du = dtv * u;
            const float* pb = projBC + r * 32;
            float Bv[DSTATE], Cv[DSTATE];
            *(float4*)&Bv[0]  = *(const float4*)&pb[0];
            *(float4*)&Bv[4]  = *(const float4*)&pb[4];
            *(float4*)&Bv[8]  = *(const float4*)&pb[8];
            *(float4*)&Bv[12] = *(const float4*)&pb[12];
            *(float4*)&Cv[0]  = *(const float4*)&pb[16];
            *(float4*)&Cv[4]  = *(const float4*)&pb[20];
            *(float4*)&Cv[8]  = *(const float4*)&pb[24];
            *(float4*)&Cv[12] = *(const float4*)&pb[28];
            float q = __expf(dtv * a0);
            float dA = q;
            h[0] = h[0] * dA + du * Bv[0];
            float y = h[0] * Cv[0];
#pragma unroll
            for (int s = 1; s < DSTATE; s++) {
                dA *= q;
                h[s] = h[s] * dA + du * Bv[s];
                y = fmaf(h[s], Cv[s], y);
            }
            float z = bf2f((unsigned short)xzBf[r * 768 + DINNER + d]);
            float val = (y + u * Dd) * (z / (1.f + __expf(-z)));
            yh[r * DINNER + d] = (short)f2bf_rne(val);
        }
    } else {
        for (int l = 0; l < LC; l++) {
            size_t r = rbase + l;
            float dtv = bf2f((unsigned short)dtB[r * DINNER + d]);
            float u = bf2f((unsigned short)xcB[r * DINNER + d]);
            float du = dtv * u;
            const float* pb = projBC + r * 32;
            float Bv[DSTATE], Cv[DSTATE];
            *(float4*)&Bv[0]  = *(const float4*)&pb[0];
            *(float4*)&Bv[4]  = *(const float4*)&pb[4];
            *(float4*)&Bv[8]  = *(const float4*)&pb[8];
            *(float4*)&Bv[12] = *(const float4*)&pb[12];
            *(float4*)&Cv[0]  = *(const float4*)&pb[16];
            *(float4*)&Cv[4]  = *(const float4*)&pb[20];
            *(float4*)&Cv[8]  = *(const float4*)&pb[24];
            *(float4*)&Cv[12] = *(const float4*)&pb[28];
            float y = 0.f;
#pragma unroll
            for (int s = 0; s < DSTATE; s++) {
                float dA = __expf(dtv * a[s]);
                h[s] = h[s] * dA + du * Bv[s];
                y = fmaf(h[s], Cv[s], y);
            }
            float z = bf2f((unsigned short)xzBf[r * 768 + DINNER + d]);
            float val = (y + u * Dd) * (z / (1.f + __expf(-z)));
            yh[r * DINNER + d] = (short)f2bf_rne(val);
        }
    }
}

// ---------------- final layernorm: per-row stats (bf16 x input) ----------------
__global__ __launch_bounds__(256) void ln_stats_kernel(const short* __restrict__ xh,
                                                       float* __restrict__ stats) {
    int r = blockIdx.x * 4 + (threadIdx.x >> 6);
    int lane = threadIdx.x & 63;
    if (r >= RTOT) return;
    float s = 0.f, ss = 0.f;
    for (int c = lane; c < DM; c += 64) {
        float v = bf2f((unsigned short)xh[(size_t)r * DM + c]);
        s += v;
        ss += v * v;
    }
#pragma unroll
    for (int o = 32; o > 0; o >>= 1) {
        s += __shfl_down(s, o);
        ss += __shfl_down(ss, o);
    }
    if (lane == 0) {
        float mu = s / (float)DM;
        float var = ss / (float)DM - mu * mu;
        stats[r * 2] = mu;
        stats[r * 2 + 1] = rsqrtf(var + 1e-5f);
    }
}

// ---------------- normalized mean over sequence (bf16 x input) ----------------
__global__ __launch_bounds__(256) void ln_mean_kernel(const short* __restrict__ xh,
                                                      const float* __restrict__ stats,
                                                      const float* __restrict__ nw,
                                                      const float* __restrict__ nb,
                                                      float* __restrict__ out) {
    int idx = blockIdx.x * 256 + threadIdx.x;
    if (idx >= BB * DM) return;
    int c = idx % DM;
    int b = idx / DM;
    float acc = 0.f;
    for (int l = 0; l < NP; l++) {
        size_t r = (size_t)b * NP + l;
        float v = bf2f((unsigned short)xh[r * DM + c]);
        acc += (v - stats[r * 2]) * stats[r * 2 + 1];
    }
    out[idx] = acc * (1.f / (float)NP) * nw[c] + nb[c];
}

extern "C" void kernel_launch(void* const* d_in, const int* in_sizes, int n_in,
                              void* d_out, int out_size, void* d_ws, size_t ws_size,
                              hipStream_t stream) {
    const float* img     = (const float*)d_in[0];
    const float* patch_w = (const float*)d_in[1];
    const float* patch_b = (const float*)d_in[2];
    const float* in_w    = (const float*)d_in[3];
    const float* conv_w  = (const float*)d_in[4];
    const float* conv_b  = (const float*)d_in[5];
    const float* xpw     = (const float*)d_in[6];
    const float* dtw     = (const float*)d_in[7];
    const float* dtb     = (const float*)d_in[8];
    const float* A_log   = (const float*)d_in[9];
    const float* Dv      = (const float*)d_in[10];
    const float* outw    = (const float*)d_in[11];
    const float* norm_w  = (const float*)d_in[12];
    const float* norm_b  = (const float*)d_in[13];
    float* out = (float*)d_out;

    float* ws = (float*)d_ws;
    const size_t R = RTOT;
    const size_t SCN = (size_t)BB * CHUNKS * DINNER * DSTATE;   // 5,505,024 elems
    const size_t PLY = R * DINNER;                              // 4,816,896 shorts

    float* xA      = ws;                       // patch-embed x bf16 / final x bf16
    float* xB      = xA + R * DM / 2;
    float* xzB     = xB + R * DM / 2;          // xz bf16 (also im2col col)
    float* xcB     = xzB + R * 768 / 2;        // xc bf16
    float* dtBf    = xcB + R * DINNER / 2;     // dt bf16
    float* projBC  = dtBf + R * DINNER / 2;    // R*32 fp32
    float* scratch = projBC + R * 32;          // 2*SCN fu shared region
    float* wAll    = scratch + 2 * SCN;        // packed weights
    float* wCrossF = wAll + 4644864;           // 23*768*384 shorts = 3,391,488 fu
    float* stats   = wCrossF + 3391488;        // R*2

    short* wPatch = (short*)wAll;                           // 192*768
    short* wIn    = wPatch + (size_t)DM * 768;              // 24*768*192
    short* wOut   = wIn + (size_t)DEPTH * 2 * DINNER * DM;  // 24*192*384
    short* wCmb   = wOut + (size_t)DEPTH * DM * DINNER;     // 24*416*384
    short* wCross = (short*)wCrossF;                        // 23*768*384

    // scan-state layout inside scratch (time-disjoint with patch partials / wOutT):
    short* hEndB  = (short*)scratch;                        // SCN shorts (2.75M fu)
    short* hInitB = hEndB + SCN;                            // SCN shorts (2.75M fu)
    float* sdtBuf = scratch + SCN;                          // BB*CHUNKS*DINNER fu (344k)
    short* y2h    = (short*)(sdtBuf + (size_t)BB * CHUNKS * DINNER);   // PLY shorts (2.4M fu)
    short* wOutT  = (short*)scratch;                        // preprocessing only

    // ---- pre-pack weights + combined xproj/dt weight + MFMA cross-layer weights ----
    pack_w_kernel<<<dim3((DM * 768 / 4 + 255) / 256), 256, 0, stream>>>(
        patch_w, wPatch, DM * 768);
    pack_w_kernel<<<dim3((DEPTH * 2 * DINNER * DM / 4 + 255) / 256), 256, 0, stream>>>(
        in_w, wIn, DEPTH * 2 * DINNER * DM);
    pack_w_kernel<<<dim3((DEPTH * DM * DINNER / 4 + 255) / 256), 256, 0, stream>>>(
        outw, wOut, DEPTH * DM * DINNER);
    wcmb_kernel<<<dim3((DEPTH * NCMB * DINNER + 255) / 256), 256, 0, stream>>>(
        xpw, dtw, wCmb);
    packT_out_kernel<<<dim3((DEPTH * DM * DINNER + 255) / 256), 256, 0, stream>>>(
        outw, wOutT);
    gemm_wcross_kernel<<<dim3(DINNER / 64, 768 / 64, DEPTH - 1), 256, 0, stream>>>(
        wIn, wOutT, wCross);

    // ---- patch embed: bf16 im2col + SK4 GEMM + reduce(+bias) -> bf16 x0 ----
    {
        short* colH = (short*)xzB;
        size_t n = R * 768;
        im2col_pack_kernel<<<dim3((unsigned)((n + 255) / 256)), 256, 0, stream>>>(img, colH);
        gemm_pk_kernel<64, 64><<<dim3(3, RTOT / 64, 4), 256, 0, stream>>>(
            colH, wPatch, scratch, nullptr, nullptr, RTOT, DM, 768, 192);
        long MN = (long)RTOT * DM;
        reduce_kernel<<<dim3((unsigned)((MN / 4 + 255) / 256)), 256, 0, stream>>>(
            scratch, (short*)xA, patch_b, MN, DM, 4);
    }

    short* xzH = (short*)xzB;
    short* xcH = (short*)xcB;
    short* dtH = (short*)dtBf;

    // layer-0 in_proj: xz(bf16) = x0 @ in_w[0]^T   (N=768, K=192)
    gemm_pk_kernel<64, 128><<<dim3(768 / 128, RTOT / 64, 1), 256, 0, stream>>>(
        (short*)xA, wIn, nullptr, xzH, nullptr, RTOT, 2 * DINNER, DM, DM);

    for (int layer = 0; layer < DEPTH; layer++) {
        const float* conv_wl = conv_w + (size_t)layer * DINNER * DCONV;
        const float* conv_bl = conv_b + (size_t)layer * DINNER;
        const float* dtb_l   = dtb + (size_t)layer * DINNER;
        const float* Alog_l  = A_log + (size_t)layer * DINNER * DSTATE;
        const float* Dv_l    = Dv + (size_t)layer * DINNER;
        short* wCmb_l = wCmb + (size_t)layer * NCMB * DINNER;

        // xc(bf16) = silu(causal depthwise conv(xs bf16)) — 4 channels/thread
        {
            size_t n = R * (DINNER / 4);
            conv_silu_kernel<<<dim3((unsigned)((n + 255) / 256)), 256, 0, stream>>>(
                xzH, conv_wl, conv_bl, xcH);
        }
        // fused xproj: [B,C -> projBC fp32 | dt -> softplus bf16]  (N=416, K=384)
        gemm_xproj_kernel<<<dim3(7, RTOT / 64), 256, 0, stream>>>(
            xcH, wCmb_l, projBC, dtH, dtb_l, RTOT, DINNER);
        // chunked scan (compressed state: hEnd bf16 + sdt scalar; hInit bf16)
        scanA_kernel<<<dim3(3, CHUNKS, BB), 128, 0, stream>>>(
            xcH, projBC, dtH, Alog_l, hEndB, sdtBuf);
        scanB_kernel<<<dim3((BB * DINNER * DSTATE + 255) / 256), 256, 0, stream>>>(
            hEndB, sdtBuf, Alog_l, hInitB);
        scanC_kernel<<<dim3(3, CHUNKS, BB), 128, 0, stream>>>(
            xcH, projBC, dtH, hInitB, Alog_l, Dv_l, xzH, y2h);
        if (layer < DEPTH - 1) {
            // fused cross-layer: xz_next(bf16) = y2 @ Wcross[layer]^T (N=768, K=384)
            short* wX = wCross + (size_t)layer * 768 * DINNER;
            gemm_pk_kernel<64, 128><<<dim3(768 / 128, RTOT / 64, 1), 256, 0, stream>>>(
                y2h, wX, nullptr, xzH, nullptr, RTOT, 2 * DINNER, DINNER, DINNER);
        } else {
            // final out_proj: x(bf16) = y2 @ outw[23]^T (N=192, K=384)
            short* wOut_l = wOut + (size_t)layer * DM * DINNER;
            gemm_pk_kernel<64, 64><<<dim3(DM / 64, RTOT / 64, 1), 256, 0, stream>>>(
                y2h, wOut_l, nullptr, (short*)xB, nullptr, RTOT, DM, DINNER, DINNER);
        }
    }

    // final layernorm + mean over sequence (bf16 x)
    short* xfH = (short*)xB;
    ln_stats_kernel<<<dim3(RTOT / 4), 256, 0, stream>>>(xfH, stats);
    ln_mean_kernel<<<dim3((BB * DM + 255) / 256), 256, 0, stream>>>(
        xfH, stats, norm_w, norm_b, out);
}